// Round 4
// baseline (6006.423 us; speedup 1.0000x reference)
//
#include <hip/hip_runtime.h>

// 2-layer GCN, R4: feature-chunked XCD-pinned aggregation + MFMA bf16 GEMMs
// + single-pass bucketed CSR build.
// Layouts: h tables are chunk-major bf16: h_t[chunk][node][16 feats] (32B per
// (chunk,node), chunk region 3.2MB = L2-resident on one XCD).

#define N_NODES 100000
#define STRIPE_SZ 12500           // 8 stripes of 12500 nodes
#define STRIPE_MAGIC 343598u      // ceil(2^32/12500): stripe = umulhi(d, MAGIC)

typedef __attribute__((ext_vector_type(8))) short short8;
typedef __attribute__((ext_vector_type(4))) float f32x4;

// ---------- bf16 helpers (RN-even) ----------
__device__ __forceinline__ unsigned short f2bf(float f) {
    union { float f; unsigned u; } c; c.f = f;
    unsigned r = (c.u + 0x7fffu + ((c.u >> 16) & 1u)) >> 16;
    return (unsigned short)r;
}
__device__ __forceinline__ float2 bfpair(unsigned u) {
    union { float f; unsigned u; } a, b;
    a.u = u << 16; b.u = u & 0xffff0000u;
    return make_float2(a.f, b.f);
}
__device__ __forceinline__ unsigned packbf(float a, float b) {
    return (unsigned)f2bf(a) | ((unsigned)f2bf(b) << 16);
}

// ---------- edge dtype detection (one wave) ----------
__global__ void detect64_k(const unsigned long long* __restrict__ ei, int* __restrict__ flag) {
    unsigned long long v = ei[threadIdx.x & 63];
    unsigned long long bad = __ballot(v >= (1ULL << 32));
    if (threadIdx.x == 0) *flag = (bad == 0ULL) ? 1 : 0;
}

__device__ __forceinline__ int edge_at(const void* ei, int is64, long long idx) {
    if (is64) return (int)((const long long*)ei)[idx];
    return ((const int*)ei)[idx];
}

__global__ void zero_k(int* __restrict__ p, int n) {
    int i = blockIdx.x * blockDim.x + threadIdx.x;
    if (i < n) p[i] = 0;
}

// ---------- bucket + count: read ei once; append (src|dlocal<<17) to dst-stripe buckets ----------
__global__ __launch_bounds__(256) void bucket_k(const void* __restrict__ ei,
                                                const int* __restrict__ flag,
                                                int* __restrict__ cnt,   // [N] degrees
                                                int* __restrict__ bcnt,  // [8] bucket counters
                                                unsigned* __restrict__ pairs,
                                                int E, int CAP) {
    int e = blockIdx.x * 256 + threadIdx.x;
    int is64 = *flag;
    int s = 0, d = 0;
    bool valid = false;
    if (e < E) {
        s = edge_at(ei, is64, e);
        d = edge_at(ei, is64, (long long)E + e);
        valid = ((unsigned)s < (unsigned)N_NODES) && ((unsigned)d < (unsigned)N_NODES);
    }
    int b = 8;
    unsigned dlocal = 0;
    if (valid) {
        b = (int)__umulhi((unsigned)d, STRIPE_MAGIC);
        dlocal = (unsigned)d - (unsigned)b * STRIPE_SZ;
        atomicAdd(&cnt[d], 1);
    }
    int lane = threadIdx.x & 63;
    unsigned long long lt = (lane == 0) ? 0ULL : ((~0ULL) >> (64 - lane));
    for (int bb = 0; bb < 8; ++bb) {
        unsigned long long m = __ballot(b == bb);
        if (m == 0ULL) continue;
        int leader = __ffsll((unsigned long long)m) - 1;
        int nlanes = __popcll(m);
        int base = 0;
        if (lane == leader) base = atomicAdd(&bcnt[bb], nlanes);
        base = __shfl(base, leader, 64);
        if (b == bb) {
            int slot = base + __popcll(m & lt);
            if (slot < CAP)
                pairs[(size_t)bb * CAP + slot] = (unsigned)s | (dlocal << 17);
        }
    }
}

// ---------- exclusive scan, 1024 elems/block ----------
__global__ void scan1_k(const int* __restrict__ cnt, int* __restrict__ partial,
                        int* __restrict__ bsum, int n) {
    __shared__ int sm[256];
    int t = threadIdx.x;
    int base = blockIdx.x * 1024 + t * 4;
    int v[4]; int loc = 0;
#pragma unroll
    for (int j = 0; j < 4; ++j) { v[j] = (base + j < n) ? cnt[base + j] : 0; loc += v[j]; }
    sm[t] = loc; __syncthreads();
    for (int off = 1; off < 256; off <<= 1) {
        int x = (t >= off) ? sm[t - off] : 0;
        __syncthreads();
        sm[t] += x;
        __syncthreads();
    }
    int incl = sm[t];
    int run = incl - loc;
    if (t == 255) bsum[blockIdx.x] = incl;
#pragma unroll
    for (int j = 0; j < 4; ++j) {
        if (base + j < n) partial[base + j] = run;
        run += v[j];
    }
}

__global__ void scan2_k(int* __restrict__ bsum, int nb) {
    __shared__ int sm[256];
    int t = threadIdx.x;
    int v = (t < nb) ? bsum[t] : 0;
    sm[t] = v; __syncthreads();
    for (int off = 1; off < 256; off <<= 1) {
        int x = (t >= off) ? sm[t - off] : 0;
        __syncthreads();
        sm[t] += x;
        __syncthreads();
    }
    if (t < nb) bsum[t] = sm[t] - v;
}

__global__ void scan3_k(const int* __restrict__ bsum, const int* __restrict__ cnt,
                        int* __restrict__ row_ptr, int* __restrict__ pos,
                        float* __restrict__ dinv, int n) {
    int base = blockIdx.x * 1024 + threadIdx.x * 4;
    int add = bsum[blockIdx.x];
#pragma unroll
    for (int j = 0; j < 4; ++j) {
        int i = base + j;
        if (i < n) {
            int r = row_ptr[i] + add;
            row_ptr[i] = r;
            pos[i] = r;
            dinv[i] = rsqrtf((float)(cnt[i] + 1));  // +1 self-loop
        }
    }
}

// ---------- fill: stripe-pinned (blockIdx&7 -> bucket/XCD); pos+colv regions L2-local ----------
__global__ __launch_bounds__(256) void fill_k(const unsigned* __restrict__ pairs,
                                              const int* __restrict__ bcnt,
                                              int* __restrict__ pos,
                                              int* __restrict__ colv, int CAP) {
    int b = blockIdx.x & 7;
    int j = blockIdx.x >> 3;
    int FB = gridDim.x >> 3;
    int n = bcnt[b]; if (n > CAP) n = CAP;
    int dbase = b * STRIPE_SZ;
    const unsigned* pb = pairs + (size_t)b * CAP;
    for (int i = j * 256 + threadIdx.x; i < n; i += FB * 256) {
        unsigned p = __builtin_nontemporal_load(pb + i);
        int s = (int)(p & 0x1FFFFu);
        int d = dbase + (int)(p >> 17);
        int slot = atomicAdd(&pos[d], 1);
        colv[slot] = s;
    }
}

// ---------- weight prep: W^T in bf16 ----------
__global__ void prep_w_k(const float* __restrict__ W1, const float* __restrict__ W2,
                         unsigned short* __restrict__ w1bf, unsigned short* __restrict__ w2bf) {
    int i = blockIdx.x * 256 + threadIdx.x;
    if (i < 128 * 128) { int k = i >> 7, f = i & 127; w1bf[f * 128 + k] = f2bf(W1[i]); }
    if (i < 128 * 64)  { int k = i >> 6, f = i & 63;  w2bf[f * 128 + k] = f2bf(W2[i]); }
}

// ---------- GEMM1 (MFMA): h1t[c][n][16] = (x @ W1) chunk-major bf16 ----------
__global__ __launch_bounds__(256) void gemm1_k(const float* __restrict__ x,
                                               const unsigned short* __restrict__ w1bf,
                                               unsigned* __restrict__ h1t, int Nn) {
    __shared__ __align__(16) unsigned short sA[128][136];  // W1^T [feat][k]
    __shared__ __align__(16) unsigned short sB[64][136];   // x [node][k]
    int tid = threadIdx.x;
    int n0g = blockIdx.x * 64;
    {   // stage A: 2048 uint4, 8/thread
        const uint4* src = (const uint4*)w1bf;
#pragma unroll
        for (int l = 0; l < 8; ++l) {
            int idx = tid + l * 256;
            int f = idx >> 4, kq = idx & 15;
            *(uint4*)&sA[f][kq * 8] = src[idx];
        }
    }
    {   // stage B: node rows fp32 -> bf16
        int n = tid >> 2, kq = tid & 3;
        int gn = n0g + n; if (gn >= Nn) gn = Nn - 1;
        const float4* xr = (const float4*)(x + (size_t)gn * 128 + kq * 32);
        unsigned short* dst = &sB[n][kq * 32];
#pragma unroll
        for (int i = 0; i < 8; ++i) {
            float4 v = xr[i];
            dst[i * 4 + 0] = f2bf(v.x); dst[i * 4 + 1] = f2bf(v.y);
            dst[i * 4 + 2] = f2bf(v.z); dst[i * 4 + 3] = f2bf(v.w);
        }
    }
    __syncthreads();
    int wave = tid >> 6, lane = tid & 63;
    int quad = lane >> 4, l16 = lane & 15;
    f32x4 z = {0.f, 0.f, 0.f, 0.f};
    f32x4 acc[2][4];
#pragma unroll
    for (int i = 0; i < 2; ++i)
#pragma unroll
        for (int t = 0; t < 4; ++t) acc[i][t] = z;
#pragma unroll
    for (int kk = 0; kk < 4; ++kk) {
        int kb = kk * 32 + quad * 8;
        short8 a0 = *(const short8*)&sA[wave * 32 + l16][kb];
        short8 a1 = *(const short8*)&sA[wave * 32 + 16 + l16][kb];
#pragma unroll
        for (int t = 0; t < 4; ++t) {
            short8 bf = *(const short8*)&sB[t * 16 + l16][kb];
            acc[0][t] = __builtin_amdgcn_mfma_f32_16x16x32_bf16(a0, bf, acc[0][t], 0, 0, 0);
            acc[1][t] = __builtin_amdgcn_mfma_f32_16x16x32_bf16(a1, bf, acc[1][t], 0, 0, 0);
        }
    }
    // D[row=feat][col=node]: row = quad*4+reg, col = l16
#pragma unroll
    for (int mi = 0; mi < 2; ++mi) {
        int c = wave * 2 + mi;  // chunk (16 feats)
#pragma unroll
        for (int t = 0; t < 4; ++t) {
            int gn = n0g + t * 16 + l16;
            if (gn < Nn) {
                uint2 u;
                u.x = packbf(acc[mi][t][0], acc[mi][t][1]);
                u.y = packbf(acc[mi][t][2], acc[mi][t][3]);
                *(uint2*)&h1t[((size_t)c * Nn + gn) * 8 + quad * 2] = u;
            }
        }
    }
}

// ---------- GEMM2 (MFMA): h2t[c][n][16] = (hr @ W2) chunk-major bf16, A from chunk-major hr ----------
__global__ __launch_bounds__(256) void gemm2_k(const unsigned* __restrict__ hrt,
                                               const unsigned short* __restrict__ w2bf,
                                               unsigned* __restrict__ h2t, int Nn) {
    __shared__ __align__(16) unsigned short sA[64][136];  // W2^T [feat][k]
    __shared__ __align__(16) unsigned short sB[64][136];  // hr [node][k]
    int tid = threadIdx.x;
    int n0g = blockIdx.x * 64;
    {   // stage A: 1024 uint4, 4/thread
        const uint4* src = (const uint4*)w2bf;
#pragma unroll
        for (int l = 0; l < 4; ++l) {
            int idx = tid + l * 256;
            int f = idx >> 4, kq = idx & 15;
            *(uint4*)&sA[f][kq * 8] = src[idx];
        }
    }
    {   // stage B from chunk-major hr: chunks 2kq, 2kq+1
        int n = tid >> 2, kq = tid & 3;
        int gn = n0g + n; if (gn >= Nn) gn = Nn - 1;
#pragma unroll
        for (int cc = 0; cc < 2; ++cc) {
            int c = kq * 2 + cc;
            const uint4* src = (const uint4*)&hrt[((size_t)c * Nn + gn) * 8];
            *(uint4*)&sB[n][c * 16] = src[0];
            *(uint4*)&sB[n][c * 16 + 8] = src[1];
        }
    }
    __syncthreads();
    int wave = tid >> 6, lane = tid & 63;
    int quad = lane >> 4, l16 = lane & 15;
    f32x4 z = {0.f, 0.f, 0.f, 0.f};
    f32x4 acc[4];
#pragma unroll
    for (int t = 0; t < 4; ++t) acc[t] = z;
#pragma unroll
    for (int kk = 0; kk < 4; ++kk) {
        int kb = kk * 32 + quad * 8;
        short8 a = *(const short8*)&sA[wave * 16 + l16][kb];
#pragma unroll
        for (int t = 0; t < 4; ++t) {
            short8 bf = *(const short8*)&sB[t * 16 + l16][kb];
            acc[t] = __builtin_amdgcn_mfma_f32_16x16x32_bf16(a, bf, acc[t], 0, 0, 0);
        }
    }
#pragma unroll
    for (int t = 0; t < 4; ++t) {
        int gn = n0g + t * 16 + l16;
        if (gn < Nn) {
            uint2 u;
            u.x = packbf(acc[t][0], acc[t][1]);
            u.y = packbf(acc[t][2], acc[t][3]);
            *(uint2*)&h2t[((size_t)wave * Nn + gn) * 8 + quad * 2] = u;
        }
    }
}

// ---------- agg1: 8 chunks, XCD-pinned; wave=node, 8 groups x 8 lanes ----------
__global__ __launch_bounds__(256) void agg1_k(const unsigned* __restrict__ ht,
                                              const int* __restrict__ row_ptr,
                                              const int* __restrict__ cnt,
                                              const int* __restrict__ colv,
                                              const float* __restrict__ dinv,
                                              const float* __restrict__ bias,
                                              unsigned* __restrict__ outt, int Nn) {
    int c = blockIdx.x & 7;
    int bj = blockIdx.x >> 3;
    int NB = gridDim.x >> 3;
    int wave = threadIdx.x >> 6, lane = threadIdx.x & 63;
    int g = lane >> 3, f = lane & 7;
    const unsigned* hc = ht + (size_t)c * Nn * 8;
    unsigned* oc = outt + (size_t)c * Nn * 8;
    float b0 = bias[c * 16 + f * 2], b1 = bias[c * 16 + f * 2 + 1];
    for (int v = bj * 4 + wave; v < Nn; v += NB * 4) {
        float di = dinv[v];
        int start = row_ptr[v], end = start + cnt[v];
        float ax = 0.f, ay = 0.f;
        if (g == 0) {
            float2 hv = bfpair(hc[(size_t)v * 8 + f]);
            float w0 = di * di;
            ax = w0 * hv.x; ay = w0 * hv.y;
        }
        for (int e = start + g; e < end; e += 8) {
            int s = __builtin_nontemporal_load(colv + e);
            float w = di * dinv[s];
            float2 hv = bfpair(hc[(size_t)s * 8 + f]);
            ax = fmaf(w, hv.x, ax); ay = fmaf(w, hv.y, ay);
        }
        ax += __shfl_xor(ax, 8, 64);  ay += __shfl_xor(ay, 8, 64);
        ax += __shfl_xor(ax, 16, 64); ay += __shfl_xor(ay, 16, 64);
        ax += __shfl_xor(ax, 32, 64); ay += __shfl_xor(ay, 32, 64);
        if (g == 0) {
            float r0 = fmaxf(ax + b0, 0.f);
            float r1 = fmaxf(ay + b1, 0.f);
            oc[(size_t)v * 8 + f] = packbf(r0, r1);
        }
    }
}

// ---------- agg2: 4 chunks x 2 XCDs (node halves); fp32 node-major out ----------
__global__ __launch_bounds__(256) void agg2_k(const unsigned* __restrict__ ht,
                                              const int* __restrict__ row_ptr,
                                              const int* __restrict__ cnt,
                                              const int* __restrict__ colv,
                                              const float* __restrict__ dinv,
                                              const float* __restrict__ bias,
                                              float* __restrict__ out, int Nn) {
    int xcd = blockIdx.x & 7;
    int c = xcd >> 1;
    int half = xcd & 1;
    int bj = blockIdx.x >> 3;
    int NB = gridDim.x >> 3;
    int wave = threadIdx.x >> 6, lane = threadIdx.x & 63;
    int g = lane >> 3, f = lane & 7;
    const unsigned* hc = ht + (size_t)c * Nn * 8;
    float b0 = bias[c * 16 + f * 2], b1 = bias[c * 16 + f * 2 + 1];
    int vlo = half * (Nn / 2), vhi = vlo + (Nn / 2) + (half ? (Nn & 1) : 0);
    for (int v = vlo + bj * 4 + wave; v < vhi; v += NB * 4) {
        float di = dinv[v];
        int start = row_ptr[v], end = start + cnt[v];
        float ax = 0.f, ay = 0.f;
        if (g == 0) {
            float2 hv = bfpair(hc[(size_t)v * 8 + f]);
            float w0 = di * di;
            ax = w0 * hv.x; ay = w0 * hv.y;
        }
        for (int e = start + g; e < end; e += 8) {
            int s = __builtin_nontemporal_load(colv + e);
            float w = di * dinv[s];
            float2 hv = bfpair(hc[(size_t)s * 8 + f]);
            ax = fmaf(w, hv.x, ax); ay = fmaf(w, hv.y, ay);
        }
        ax += __shfl_xor(ax, 8, 64);  ay += __shfl_xor(ay, 8, 64);
        ax += __shfl_xor(ax, 16, 64); ay += __shfl_xor(ay, 16, 64);
        ax += __shfl_xor(ax, 32, 64); ay += __shfl_xor(ay, 32, 64);
        if (g == 0) {
            float2 r = make_float2(ax + b0, ay + b1);
            *(float2*)&out[(size_t)v * 64 + c * 16 + f * 2] = r;
        }
    }
}

// ---------- launch ----------
extern "C" void kernel_launch(void* const* d_in, const int* in_sizes, int n_in,
                              void* d_out, int out_size, void* d_ws, size_t ws_size,
                              hipStream_t stream) {
    const float* x  = (const float*)d_in[0];
    const void*  ei = d_in[1];
    const float* W1 = (const float*)d_in[2];
    const float* b1 = (const float*)d_in[3];
    const float* W2 = (const float*)d_in[4];
    const float* b2 = (const float*)d_in[5];

    const int N = N_NODES;
    const int E = in_sizes[1] / 2;
    const int CAP = E / 8 + 8192;

    char* w = (char*)d_ws;
    size_t off = 0;
    auto take = [&](size_t bytes) {
        void* p = w + off;
        off = (off + bytes + 255) & ~(size_t)255;
        return p;
    };
    int*   flag    = (int*)take(sizeof(int));
    int*   cnt     = (int*)take(((size_t)N + 8) * 4);  // + 8 bucket counters
    int*   bcnt    = cnt + N;
    int*   row_ptr = (int*)take((size_t)N * 4);
    int*   pos     = (int*)take((size_t)N * 4);
    int*   bsum    = (int*)take(128 * 4);
    float* dinv    = (float*)take((size_t)N * 4);
    int*   colv    = (int*)take((size_t)E * 4);
    unsigned* pairs = (unsigned*)take((size_t)8 * CAP * 4);
    unsigned short* w1bf = (unsigned short*)take(128 * 128 * 2);
    unsigned short* w2bf = (unsigned short*)take(64 * 128 * 2);
    unsigned* hrt  = (unsigned*)take((size_t)8 * N * 8 * 4);   // 25.6 MB
    unsigned* h2t  = (unsigned*)take((size_t)4 * N * 8 * 4);   // 12.8 MB
    (void)ws_size; (void)n_in; (void)out_size;

    unsigned* h1t = (unsigned*)d_out;  // 25.6 MB, dead before agg2's final write

    const int nscan = (N + 1023) / 1024;  // 98

    detect64_k<<<1, 64, 0, stream>>>((const unsigned long long*)ei, flag);
    zero_k<<<(N + 8 + 255) / 256, 256, 0, stream>>>(cnt, N + 8);
    bucket_k<<<(E + 255) / 256, 256, 0, stream>>>(ei, flag, cnt, bcnt, pairs, E, CAP);
    scan1_k<<<nscan, 256, 0, stream>>>(cnt, row_ptr, bsum, N);
    scan2_k<<<1, 256, 0, stream>>>(bsum, nscan);
    scan3_k<<<nscan, 256, 0, stream>>>(bsum, cnt, row_ptr, pos, dinv, N);
    fill_k<<<512, 256, 0, stream>>>(pairs, bcnt, pos, colv, CAP);
    prep_w_k<<<64, 256, 0, stream>>>(W1, W2, w1bf, w2bf);

    gemm1_k<<<(N + 63) / 64, 256, 0, stream>>>(x, w1bf, h1t, N);
    agg1_k<<<768, 256, 0, stream>>>(h1t, row_ptr, cnt, colv, dinv, b1, hrt, N);
    gemm2_k<<<(N + 63) / 64, 256, 0, stream>>>(hrt, w2bf, h2t, N);
    agg2_k<<<768, 256, 0, stream>>>(h2t, row_ptr, cnt, colv, dinv, b2, (float*)d_out, N);
}

// Round 5
// 1616.016 us; speedup vs baseline: 3.7168x; 3.7168x over previous
//
#include <hip/hip_runtime.h>

// 2-layer GCN, R5: R4's MFMA GEMMs + chunk-major XCD-pinned aggregation,
// with the CSR build reverted to R3's proven striped scheme (R4's bucket_k
// died on single-cache-line atomic serialization: 4.6ms, VALUBusy 0.4%).
// h tables chunk-major bf16: h_t[chunk][node][16 feats].

#define N_NODES 100000
#define STRIPE_SZ 12500  // 8 stripes

typedef __attribute__((ext_vector_type(8))) short short8;
typedef __attribute__((ext_vector_type(4))) float f32x4;

// ---------- bf16 helpers (RN-even) ----------
__device__ __forceinline__ unsigned short f2bf(float f) {
    union { float f; unsigned u; } c; c.f = f;
    unsigned r = (c.u + 0x7fffu + ((c.u >> 16) & 1u)) >> 16;
    return (unsigned short)r;
}
__device__ __forceinline__ float2 bfpair(unsigned u) {
    union { float f; unsigned u; } a, b;
    a.u = u << 16; b.u = u & 0xffff0000u;
    return make_float2(a.f, b.f);
}
__device__ __forceinline__ unsigned packbf(float a, float b) {
    return (unsigned)f2bf(a) | ((unsigned)f2bf(b) << 16);
}

// ---------- edge dtype detection (one wave) ----------
__global__ void detect64_k(const unsigned long long* __restrict__ ei, int* __restrict__ flag) {
    unsigned long long v = ei[threadIdx.x & 63];
    unsigned long long bad = __ballot(v >= (1ULL << 32));
    if (threadIdx.x == 0) *flag = (bad == 0ULL) ? 1 : 0;
}

__device__ __forceinline__ int edge_at(const void* ei, int is64, long long idx) {
    if (is64) return (int)((const long long*)ei)[idx];
    return ((const int*)ei)[idx];
}

// ---------- convert edge_index -> int32 src/dst ----------
__global__ void convert_k(const void* __restrict__ ei, const int* __restrict__ flag,
                          int* __restrict__ esrc, int* __restrict__ edst, int E) {
    int e = blockIdx.x * blockDim.x + threadIdx.x;
    if (e >= E) return;
    int is64 = *flag;
    esrc[e] = edge_at(ei, is64, e);
    edst[e] = edge_at(ei, is64, (long long)E + e);
}

__global__ void zero_k(int* __restrict__ p, int n) {
    int i = blockIdx.x * blockDim.x + threadIdx.x;
    if (i < n) p[i] = 0;
}

// ---------- degree count (atomics spread over N addresses — proven fine) ----------
__global__ void count_k(const int* __restrict__ edst, int* __restrict__ cnt, int E) {
    int e = blockIdx.x * blockDim.x + threadIdx.x;
    if (e >= E) return;
    int d = edst[e];
    if ((unsigned)d < (unsigned)N_NODES) atomicAdd(&cnt[d], 1);
}

// ---------- exclusive scan, 1024 elems/block ----------
__global__ void scan1_k(const int* __restrict__ cnt, int* __restrict__ partial,
                        int* __restrict__ bsum, int n) {
    __shared__ int sm[256];
    int t = threadIdx.x;
    int base = blockIdx.x * 1024 + t * 4;
    int v[4]; int loc = 0;
#pragma unroll
    for (int j = 0; j < 4; ++j) { v[j] = (base + j < n) ? cnt[base + j] : 0; loc += v[j]; }
    sm[t] = loc; __syncthreads();
    for (int off = 1; off < 256; off <<= 1) {
        int x = (t >= off) ? sm[t - off] : 0;
        __syncthreads();
        sm[t] += x;
        __syncthreads();
    }
    int incl = sm[t];
    int run = incl - loc;
    if (t == 255) bsum[blockIdx.x] = incl;
#pragma unroll
    for (int j = 0; j < 4; ++j) {
        if (base + j < n) partial[base + j] = run;
        run += v[j];
    }
}

__global__ void scan2_k(int* __restrict__ bsum, int nb) {
    __shared__ int sm[256];
    int t = threadIdx.x;
    int v = (t < nb) ? bsum[t] : 0;
    sm[t] = v; __syncthreads();
    for (int off = 1; off < 256; off <<= 1) {
        int x = (t >= off) ? sm[t - off] : 0;
        __syncthreads();
        sm[t] += x;
        __syncthreads();
    }
    if (t < nb) bsum[t] = sm[t] - v;
}

__global__ void scan3_k(const int* __restrict__ bsum, const int* __restrict__ cnt,
                        int* __restrict__ row_ptr, int* __restrict__ pos,
                        float* __restrict__ dinv, int n) {
    int base = blockIdx.x * 1024 + threadIdx.x * 4;
    int add = bsum[blockIdx.x];
#pragma unroll
    for (int j = 0; j < 4; ++j) {
        int i = base + j;
        if (i < n) {
            int r = row_ptr[i] + add;
            row_ptr[i] = r;
            pos[i] = r;
            dinv[i] = rsqrtf((float)(cnt[i] + 1));  // +1 self-loop
        }
    }
}

// ---------- striped CSR fill (R3-proven): stripes sequential, active region L2-resident ----------
__global__ __launch_bounds__(256) void fill_stripe_k(const int* __restrict__ esrc,
                                                     const int* __restrict__ edst,
                                                     int* __restrict__ pos,
                                                     int* __restrict__ colv, int E) {
    int stride = gridDim.x * blockDim.x;
    int tid = blockIdx.x * blockDim.x + threadIdx.x;
    for (int s = 0; s < 8; ++s) {
        for (int e = tid; e < E; e += stride) {
            int d = edst[e];
            if ((unsigned)d >= (unsigned)N_NODES) continue;
            if (d / STRIPE_SZ != s) continue;
            int sv = esrc[e];
            int slot = atomicAdd(&pos[d], 1);
            colv[slot] = sv;
        }
    }
}

// ---------- weight prep: W^T in bf16 ----------
__global__ void prep_w_k(const float* __restrict__ W1, const float* __restrict__ W2,
                         unsigned short* __restrict__ w1bf, unsigned short* __restrict__ w2bf) {
    int i = blockIdx.x * 256 + threadIdx.x;
    if (i < 128 * 128) { int k = i >> 7, f = i & 127; w1bf[f * 128 + k] = f2bf(W1[i]); }
    if (i < 128 * 64)  { int k = i >> 6, f = i & 63;  w2bf[f * 128 + k] = f2bf(W2[i]); }
}

// ---------- GEMM1 (MFMA): h1t[c][n][16] = (x @ W1) chunk-major bf16 ----------
__global__ __launch_bounds__(256) void gemm1_k(const float* __restrict__ x,
                                               const unsigned short* __restrict__ w1bf,
                                               unsigned* __restrict__ h1t, int Nn) {
    __shared__ __align__(16) unsigned short sA[128][136];  // W1^T [feat][k]
    __shared__ __align__(16) unsigned short sB[64][136];   // x [node][k]
    int tid = threadIdx.x;
    int n0g = blockIdx.x * 64;
    {   // stage A: 2048 uint4, 8/thread
        const uint4* src = (const uint4*)w1bf;
#pragma unroll
        for (int l = 0; l < 8; ++l) {
            int idx = tid + l * 256;
            int f = idx >> 4, kq = idx & 15;
            *(uint4*)&sA[f][kq * 8] = src[idx];
        }
    }
    {   // stage B: node rows fp32 -> bf16
        int n = tid >> 2, kq = tid & 3;
        int gn = n0g + n; if (gn >= Nn) gn = Nn - 1;
        const float4* xr = (const float4*)(x + (size_t)gn * 128 + kq * 32);
        unsigned short* dst = &sB[n][kq * 32];
#pragma unroll
        for (int i = 0; i < 8; ++i) {
            float4 v = xr[i];
            dst[i * 4 + 0] = f2bf(v.x); dst[i * 4 + 1] = f2bf(v.y);
            dst[i * 4 + 2] = f2bf(v.z); dst[i * 4 + 3] = f2bf(v.w);
        }
    }
    __syncthreads();
    int wave = tid >> 6, lane = tid & 63;
    int quad = lane >> 4, l16 = lane & 15;
    f32x4 z = {0.f, 0.f, 0.f, 0.f};
    f32x4 acc[2][4];
#pragma unroll
    for (int i = 0; i < 2; ++i)
#pragma unroll
        for (int t = 0; t < 4; ++t) acc[i][t] = z;
#pragma unroll
    for (int kk = 0; kk < 4; ++kk) {
        int kb = kk * 32 + quad * 8;
        short8 a0 = *(const short8*)&sA[wave * 32 + l16][kb];
        short8 a1 = *(const short8*)&sA[wave * 32 + 16 + l16][kb];
#pragma unroll
        for (int t = 0; t < 4; ++t) {
            short8 bf = *(const short8*)&sB[t * 16 + l16][kb];
            acc[0][t] = __builtin_amdgcn_mfma_f32_16x16x32_bf16(a0, bf, acc[0][t], 0, 0, 0);
            acc[1][t] = __builtin_amdgcn_mfma_f32_16x16x32_bf16(a1, bf, acc[1][t], 0, 0, 0);
        }
    }
    // D[row=feat][col=node]: row = quad*4+reg, col = l16
#pragma unroll
    for (int mi = 0; mi < 2; ++mi) {
        int c = wave * 2 + mi;  // chunk (16 feats)
#pragma unroll
        for (int t = 0; t < 4; ++t) {
            int gn = n0g + t * 16 + l16;
            if (gn < Nn) {
                uint2 u;
                u.x = packbf(acc[mi][t][0], acc[mi][t][1]);
                u.y = packbf(acc[mi][t][2], acc[mi][t][3]);
                *(uint2*)&h1t[((size_t)c * Nn + gn) * 8 + quad * 2] = u;
            }
        }
    }
}

// ---------- GEMM2 (MFMA): h2t[c][n][16] = (hr @ W2) chunk-major bf16 ----------
__global__ __launch_bounds__(256) void gemm2_k(const unsigned* __restrict__ hrt,
                                               const unsigned short* __restrict__ w2bf,
                                               unsigned* __restrict__ h2t, int Nn) {
    __shared__ __align__(16) unsigned short sA[64][136];  // W2^T [feat][k]
    __shared__ __align__(16) unsigned short sB[64][136];  // hr [node][k]
    int tid = threadIdx.x;
    int n0g = blockIdx.x * 64;
    {   // stage A: 1024 uint4, 4/thread
        const uint4* src = (const uint4*)w2bf;
#pragma unroll
        for (int l = 0; l < 4; ++l) {
            int idx = tid + l * 256;
            int f = idx >> 4, kq = idx & 15;
            *(uint4*)&sA[f][kq * 8] = src[idx];
        }
    }
    {   // stage B from chunk-major hr: chunks 2kq, 2kq+1
        int n = tid >> 2, kq = tid & 3;
        int gn = n0g + n; if (gn >= Nn) gn = Nn - 1;
#pragma unroll
        for (int cc = 0; cc < 2; ++cc) {
            int c = kq * 2 + cc;
            const uint4* src = (const uint4*)&hrt[((size_t)c * Nn + gn) * 8];
            *(uint4*)&sB[n][c * 16] = src[0];
            *(uint4*)&sB[n][c * 16 + 8] = src[1];
        }
    }
    __syncthreads();
    int wave = tid >> 6, lane = tid & 63;
    int quad = lane >> 4, l16 = lane & 15;
    f32x4 z = {0.f, 0.f, 0.f, 0.f};
    f32x4 acc[4];
#pragma unroll
    for (int t = 0; t < 4; ++t) acc[t] = z;
#pragma unroll
    for (int kk = 0; kk < 4; ++kk) {
        int kb = kk * 32 + quad * 8;
        short8 a = *(const short8*)&sA[wave * 16 + l16][kb];
#pragma unroll
        for (int t = 0; t < 4; ++t) {
            short8 bf = *(const short8*)&sB[t * 16 + l16][kb];
            acc[t] = __builtin_amdgcn_mfma_f32_16x16x32_bf16(a, bf, acc[t], 0, 0, 0);
        }
    }
#pragma unroll
    for (int t = 0; t < 4; ++t) {
        int gn = n0g + t * 16 + l16;
        if (gn < Nn) {
            uint2 u;
            u.x = packbf(acc[t][0], acc[t][1]);
            u.y = packbf(acc[t][2], acc[t][3]);
            *(uint2*)&h2t[((size_t)wave * Nn + gn) * 8 + quad * 2] = u;
        }
    }
}

// ---------- agg1: 8 chunks, XCD-pinned (blockIdx&7); wave=node, 8 groups x 8 lanes ----------
__global__ __launch_bounds__(256) void agg1_k(const unsigned* __restrict__ ht,
                                              const int* __restrict__ row_ptr,
                                              const int* __restrict__ cnt,
                                              const int* __restrict__ colv,
                                              const float* __restrict__ dinv,
                                              const float* __restrict__ bias,
                                              unsigned* __restrict__ outt, int Nn) {
    int c = blockIdx.x & 7;
    int bj = blockIdx.x >> 3;
    int NB = gridDim.x >> 3;
    int wave = threadIdx.x >> 6, lane = threadIdx.x & 63;
    int g = lane >> 3, f = lane & 7;
    const unsigned* hc = ht + (size_t)c * Nn * 8;
    unsigned* oc = outt + (size_t)c * Nn * 8;
    float b0 = bias[c * 16 + f * 2], b1 = bias[c * 16 + f * 2 + 1];
    for (int v = bj * 4 + wave; v < Nn; v += NB * 4) {
        float di = dinv[v];
        int start = row_ptr[v], end = start + cnt[v];
        float ax = 0.f, ay = 0.f;
        if (g == 0) {
            float2 hv = bfpair(hc[(size_t)v * 8 + f]);
            float w0 = di * di;
            ax = w0 * hv.x; ay = w0 * hv.y;
        }
        for (int e = start + g; e < end; e += 8) {
            int s = __builtin_nontemporal_load(colv + e);
            float w = di * dinv[s];
            float2 hv = bfpair(hc[(size_t)s * 8 + f]);
            ax = fmaf(w, hv.x, ax); ay = fmaf(w, hv.y, ay);
        }
        ax += __shfl_xor(ax, 8, 64);  ay += __shfl_xor(ay, 8, 64);
        ax += __shfl_xor(ax, 16, 64); ay += __shfl_xor(ay, 16, 64);
        ax += __shfl_xor(ax, 32, 64); ay += __shfl_xor(ay, 32, 64);
        if (g == 0) {
            float r0 = fmaxf(ax + b0, 0.f);
            float r1 = fmaxf(ay + b1, 0.f);
            oc[(size_t)v * 8 + f] = packbf(r0, r1);
        }
    }
}

// ---------- agg2: 4 chunks x 2 node-halves; fp32 node-major out ----------
__global__ __launch_bounds__(256) void agg2_k(const unsigned* __restrict__ ht,
                                              const int* __restrict__ row_ptr,
                                              const int* __restrict__ cnt,
                                              const int* __restrict__ colv,
                                              const float* __restrict__ dinv,
                                              const float* __restrict__ bias,
                                              float* __restrict__ out, int Nn) {
    int xcd = blockIdx.x & 7;
    int c = xcd >> 1;
    int half = xcd & 1;
    int bj = blockIdx.x >> 3;
    int NB = gridDim.x >> 3;
    int wave = threadIdx.x >> 6, lane = threadIdx.x & 63;
    int g = lane >> 3, f = lane & 7;
    const unsigned* hc = ht + (size_t)c * Nn * 8;
    float b0 = bias[c * 16 + f * 2], b1 = bias[c * 16 + f * 2 + 1];
    int vlo = half * (Nn / 2), vhi = vlo + (Nn / 2) + (half ? (Nn & 1) : 0);
    for (int v = vlo + bj * 4 + wave; v < vhi; v += NB * 4) {
        float di = dinv[v];
        int start = row_ptr[v], end = start + cnt[v];
        float ax = 0.f, ay = 0.f;
        if (g == 0) {
            float2 hv = bfpair(hc[(size_t)v * 8 + f]);
            float w0 = di * di;
            ax = w0 * hv.x; ay = w0 * hv.y;
        }
        for (int e = start + g; e < end; e += 8) {
            int s = __builtin_nontemporal_load(colv + e);
            float w = di * dinv[s];
            float2 hv = bfpair(hc[(size_t)s * 8 + f]);
            ax = fmaf(w, hv.x, ax); ay = fmaf(w, hv.y, ay);
        }
        ax += __shfl_xor(ax, 8, 64);  ay += __shfl_xor(ay, 8, 64);
        ax += __shfl_xor(ax, 16, 64); ay += __shfl_xor(ay, 16, 64);
        ax += __shfl_xor(ax, 32, 64); ay += __shfl_xor(ay, 32, 64);
        if (g == 0) {
            float2 r = make_float2(ax + b0, ay + b1);
            *(float2*)&out[(size_t)v * 64 + c * 16 + f * 2] = r;
        }
    }
}

// ---------- launch ----------
extern "C" void kernel_launch(void* const* d_in, const int* in_sizes, int n_in,
                              void* d_out, int out_size, void* d_ws, size_t ws_size,
                              hipStream_t stream) {
    const float* x  = (const float*)d_in[0];
    const void*  ei = d_in[1];
    const float* W1 = (const float*)d_in[2];
    const float* b1 = (const float*)d_in[3];
    const float* W2 = (const float*)d_in[4];
    const float* b2 = (const float*)d_in[5];

    const int N = N_NODES;
    const int E = in_sizes[1] / 2;

    char* w = (char*)d_ws;
    size_t off = 0;
    auto take = [&](size_t bytes) {
        void* p = w + off;
        off = (off + bytes + 255) & ~(size_t)255;
        return p;
    };
    int*   flag    = (int*)take(sizeof(int));
    int*   cnt     = (int*)take((size_t)N * 4);
    int*   row_ptr = (int*)take((size_t)N * 4);
    int*   pos     = (int*)take((size_t)N * 4);
    int*   bsum    = (int*)take(128 * 4);
    float* dinv    = (float*)take((size_t)N * 4);
    int*   esrc    = (int*)take((size_t)E * 4);
    int*   edst    = (int*)take((size_t)E * 4);
    int*   colv    = (int*)take((size_t)E * 4);
    unsigned short* w1bf = (unsigned short*)take(128 * 128 * 2);
    unsigned short* w2bf = (unsigned short*)take(64 * 128 * 2);
    unsigned* hrt  = (unsigned*)take((size_t)8 * N * 8 * 4);   // 25.6 MB
    unsigned* h2t  = (unsigned*)take((size_t)4 * N * 8 * 4);   // 12.8 MB
    (void)ws_size; (void)n_in; (void)out_size;

    unsigned* h1t = (unsigned*)d_out;  // 25.6 MB, dead before agg2's final write

    const int nscan = (N + 1023) / 1024;  // 98

    detect64_k<<<1, 64, 0, stream>>>((const unsigned long long*)ei, flag);
    convert_k<<<(E + 255) / 256, 256, 0, stream>>>(ei, flag, esrc, edst, E);
    zero_k<<<(N + 255) / 256, 256, 0, stream>>>(cnt, N);
    count_k<<<(E + 255) / 256, 256, 0, stream>>>(edst, cnt, E);
    scan1_k<<<nscan, 256, 0, stream>>>(cnt, row_ptr, bsum, N);
    scan2_k<<<1, 256, 0, stream>>>(bsum, nscan);
    scan3_k<<<nscan, 256, 0, stream>>>(bsum, cnt, row_ptr, pos, dinv, N);
    fill_stripe_k<<<1024, 256, 0, stream>>>(esrc, edst, pos, colv, E);
    prep_w_k<<<64, 256, 0, stream>>>(W1, W2, w1bf, w2bf);

    gemm1_k<<<(N + 63) / 64, 256, 0, stream>>>(x, w1bf, h1t, N);
    agg1_k<<<768, 256, 0, stream>>>(h1t, row_ptr, cnt, colv, dinv, b1, hrt, N);
    gemm2_k<<<(N + 63) / 64, 256, 0, stream>>>(hrt, w2bf, h2t, N);
    agg2_k<<<768, 256, 0, stream>>>(h2t, row_ptr, cnt, colv, dinv, b2, (float*)d_out, N);
}

// Round 6
// 1025.759 us; speedup vs baseline: 5.8556x; 1.5754x over previous
//
#include <hip/hip_runtime.h>

// 2-layer GCN, R6: R5 structure (chunk-major XCD-pinned agg + MFMA GEMMs +
// striped CSR fill) with agg parallelism restored: 25000 blocks (R5's 768-block
// persistent grid was latency-bound at 33% occupancy: 780us, VALUBusy 14%).
// h tables chunk-major bf16: h_t[chunk][node][16 feats] (3.2MB chunk = L2-size).

#define N_NODES 100000
#define STRIPE_SZ 12500  // 8 stripes

typedef __attribute__((ext_vector_type(8))) short short8;
typedef __attribute__((ext_vector_type(4))) float f32x4;

// ---------- bf16 helpers (RN-even) ----------
__device__ __forceinline__ unsigned short f2bf(float f) {
    union { float f; unsigned u; } c; c.f = f;
    unsigned r = (c.u + 0x7fffu + ((c.u >> 16) & 1u)) >> 16;
    return (unsigned short)r;
}
__device__ __forceinline__ float2 bfpair(unsigned u) {
    union { float f; unsigned u; } a, b;
    a.u = u << 16; b.u = u & 0xffff0000u;
    return make_float2(a.f, b.f);
}
__device__ __forceinline__ unsigned packbf(float a, float b) {
    return (unsigned)f2bf(a) | ((unsigned)f2bf(b) << 16);
}

// ---------- edge dtype detection (one wave) ----------
__global__ void detect64_k(const unsigned long long* __restrict__ ei, int* __restrict__ flag) {
    unsigned long long v = ei[threadIdx.x & 63];
    unsigned long long bad = __ballot(v >= (1ULL << 32));
    if (threadIdx.x == 0) *flag = (bad == 0ULL) ? 1 : 0;
}

__device__ __forceinline__ int edge_at(const void* ei, int is64, long long idx) {
    if (is64) return (int)((const long long*)ei)[idx];
    return ((const int*)ei)[idx];
}

// ---------- convert edge_index -> int32 src/dst ----------
__global__ void convert_k(const void* __restrict__ ei, const int* __restrict__ flag,
                          int* __restrict__ esrc, int* __restrict__ edst, int E) {
    int e = blockIdx.x * blockDim.x + threadIdx.x;
    if (e >= E) return;
    int is64 = *flag;
    esrc[e] = edge_at(ei, is64, e);
    edst[e] = edge_at(ei, is64, (long long)E + e);
}

__global__ void zero_k(int* __restrict__ p, int n) {
    int i = blockIdx.x * blockDim.x + threadIdx.x;
    if (i < n) p[i] = 0;
}

// ---------- degree count ----------
__global__ void count_k(const int* __restrict__ edst, int* __restrict__ cnt, int E) {
    int e = blockIdx.x * blockDim.x + threadIdx.x;
    if (e >= E) return;
    int d = edst[e];
    if ((unsigned)d < (unsigned)N_NODES) atomicAdd(&cnt[d], 1);
}

// ---------- exclusive scan, 1024 elems/block ----------
__global__ void scan1_k(const int* __restrict__ cnt, int* __restrict__ partial,
                        int* __restrict__ bsum, int n) {
    __shared__ int sm[256];
    int t = threadIdx.x;
    int base = blockIdx.x * 1024 + t * 4;
    int v[4]; int loc = 0;
#pragma unroll
    for (int j = 0; j < 4; ++j) { v[j] = (base + j < n) ? cnt[base + j] : 0; loc += v[j]; }
    sm[t] = loc; __syncthreads();
    for (int off = 1; off < 256; off <<= 1) {
        int x = (t >= off) ? sm[t - off] : 0;
        __syncthreads();
        sm[t] += x;
        __syncthreads();
    }
    int incl = sm[t];
    int run = incl - loc;
    if (t == 255) bsum[blockIdx.x] = incl;
#pragma unroll
    for (int j = 0; j < 4; ++j) {
        if (base + j < n) partial[base + j] = run;
        run += v[j];
    }
}

__global__ void scan2_k(int* __restrict__ bsum, int nb) {
    __shared__ int sm[256];
    int t = threadIdx.x;
    int v = (t < nb) ? bsum[t] : 0;
    sm[t] = v; __syncthreads();
    for (int off = 1; off < 256; off <<= 1) {
        int x = (t >= off) ? sm[t - off] : 0;
        __syncthreads();
        sm[t] += x;
        __syncthreads();
    }
    if (t < nb) bsum[t] = sm[t] - v;
}

__global__ void scan3_k(const int* __restrict__ bsum, const int* __restrict__ cnt,
                        int* __restrict__ row_ptr, int* __restrict__ pos,
                        float* __restrict__ dinv, int n) {
    int base = blockIdx.x * 1024 + threadIdx.x * 4;
    int add = bsum[blockIdx.x];
#pragma unroll
    for (int j = 0; j < 4; ++j) {
        int i = base + j;
        if (i < n) {
            int r = row_ptr[i] + add;
            row_ptr[i] = r;
            pos[i] = r;
            dinv[i] = rsqrtf((float)(cnt[i] + 1));  // +1 self-loop
        }
    }
}

// ---------- striped CSR fill ----------
__global__ __launch_bounds__(256) void fill_stripe_k(const int* __restrict__ esrc,
                                                     const int* __restrict__ edst,
                                                     int* __restrict__ pos,
                                                     int* __restrict__ colv, int E) {
    int stride = gridDim.x * blockDim.x;
    int tid = blockIdx.x * blockDim.x + threadIdx.x;
    for (int s = 0; s < 8; ++s) {
        for (int e = tid; e < E; e += stride) {
            int d = edst[e];
            if ((unsigned)d >= (unsigned)N_NODES) continue;
            if (d / STRIPE_SZ != s) continue;
            int sv = esrc[e];
            int slot = atomicAdd(&pos[d], 1);
            colv[slot] = sv;
        }
    }
}

// ---------- weight prep: W^T in bf16 ----------
__global__ void prep_w_k(const float* __restrict__ W1, const float* __restrict__ W2,
                         unsigned short* __restrict__ w1bf, unsigned short* __restrict__ w2bf) {
    int i = blockIdx.x * 256 + threadIdx.x;
    if (i < 128 * 128) { int k = i >> 7, f = i & 127; w1bf[f * 128 + k] = f2bf(W1[i]); }
    if (i < 128 * 64)  { int k = i >> 6, f = i & 63;  w2bf[f * 128 + k] = f2bf(W2[i]); }
}

// ---------- GEMM1 (MFMA): h1t[c][n][16] = (x @ W1) chunk-major bf16 ----------
__global__ __launch_bounds__(256) void gemm1_k(const float* __restrict__ x,
                                               const unsigned short* __restrict__ w1bf,
                                               unsigned* __restrict__ h1t, int Nn) {
    __shared__ __align__(16) unsigned short sA[128][136];  // W1^T [feat][k]
    __shared__ __align__(16) unsigned short sB[64][136];   // x [node][k]
    int tid = threadIdx.x;
    int n0g = blockIdx.x * 64;
    {   // stage A: 2048 uint4, 8/thread
        const uint4* src = (const uint4*)w1bf;
#pragma unroll
        for (int l = 0; l < 8; ++l) {
            int idx = tid + l * 256;
            int f = idx >> 4, kq = idx & 15;
            *(uint4*)&sA[f][kq * 8] = src[idx];
        }
    }
    {   // stage B: node rows fp32 -> bf16
        int n = tid >> 2, kq = tid & 3;
        int gn = n0g + n; if (gn >= Nn) gn = Nn - 1;
        const float4* xr = (const float4*)(x + (size_t)gn * 128 + kq * 32);
        unsigned short* dst = &sB[n][kq * 32];
#pragma unroll
        for (int i = 0; i < 8; ++i) {
            float4 v = xr[i];
            dst[i * 4 + 0] = f2bf(v.x); dst[i * 4 + 1] = f2bf(v.y);
            dst[i * 4 + 2] = f2bf(v.z); dst[i * 4 + 3] = f2bf(v.w);
        }
    }
    __syncthreads();
    int wave = tid >> 6, lane = tid & 63;
    int quad = lane >> 4, l16 = lane & 15;
    f32x4 z = {0.f, 0.f, 0.f, 0.f};
    f32x4 acc[2][4];
#pragma unroll
    for (int i = 0; i < 2; ++i)
#pragma unroll
        for (int t = 0; t < 4; ++t) acc[i][t] = z;
#pragma unroll
    for (int kk = 0; kk < 4; ++kk) {
        int kb = kk * 32 + quad * 8;
        short8 a0 = *(const short8*)&sA[wave * 32 + l16][kb];
        short8 a1 = *(const short8*)&sA[wave * 32 + 16 + l16][kb];
#pragma unroll
        for (int t = 0; t < 4; ++t) {
            short8 bf = *(const short8*)&sB[t * 16 + l16][kb];
            acc[0][t] = __builtin_amdgcn_mfma_f32_16x16x32_bf16(a0, bf, acc[0][t], 0, 0, 0);
            acc[1][t] = __builtin_amdgcn_mfma_f32_16x16x32_bf16(a1, bf, acc[1][t], 0, 0, 0);
        }
    }
    // D[row=feat][col=node]: row = quad*4+reg, col = l16
#pragma unroll
    for (int mi = 0; mi < 2; ++mi) {
        int c = wave * 2 + mi;  // chunk (16 feats)
#pragma unroll
        for (int t = 0; t < 4; ++t) {
            int gn = n0g + t * 16 + l16;
            if (gn < Nn) {
                uint2 u;
                u.x = packbf(acc[mi][t][0], acc[mi][t][1]);
                u.y = packbf(acc[mi][t][2], acc[mi][t][3]);
                *(uint2*)&h1t[((size_t)c * Nn + gn) * 8 + quad * 2] = u;
            }
        }
    }
}

// ---------- GEMM2 (MFMA): h2t[c][n][16] = (hr @ W2) chunk-major bf16 ----------
__global__ __launch_bounds__(256) void gemm2_k(const unsigned* __restrict__ hrt,
                                               const unsigned short* __restrict__ w2bf,
                                               unsigned* __restrict__ h2t, int Nn) {
    __shared__ __align__(16) unsigned short sA[64][136];  // W2^T [feat][k]
    __shared__ __align__(16) unsigned short sB[64][136];  // hr [node][k]
    int tid = threadIdx.x;
    int n0g = blockIdx.x * 64;
    {   // stage A: 1024 uint4, 4/thread
        const uint4* src = (const uint4*)w2bf;
#pragma unroll
        for (int l = 0; l < 4; ++l) {
            int idx = tid + l * 256;
            int f = idx >> 4, kq = idx & 15;
            *(uint4*)&sA[f][kq * 8] = src[idx];
        }
    }
    {   // stage B from chunk-major hr: chunks 2kq, 2kq+1
        int n = tid >> 2, kq = tid & 3;
        int gn = n0g + n; if (gn >= Nn) gn = Nn - 1;
#pragma unroll
        for (int cc = 0; cc < 2; ++cc) {
            int c = kq * 2 + cc;
            const uint4* src = (const uint4*)&hrt[((size_t)c * Nn + gn) * 8];
            *(uint4*)&sB[n][c * 16] = src[0];
            *(uint4*)&sB[n][c * 16 + 8] = src[1];
        }
    }
    __syncthreads();
    int wave = tid >> 6, lane = tid & 63;
    int quad = lane >> 4, l16 = lane & 15;
    f32x4 z = {0.f, 0.f, 0.f, 0.f};
    f32x4 acc[4];
#pragma unroll
    for (int t = 0; t < 4; ++t) acc[t] = z;
#pragma unroll
    for (int kk = 0; kk < 4; ++kk) {
        int kb = kk * 32 + quad * 8;
        short8 a = *(const short8*)&sA[wave * 16 + l16][kb];
#pragma unroll
        for (int t = 0; t < 4; ++t) {
            short8 bf = *(const short8*)&sB[t * 16 + l16][kb];
            acc[t] = __builtin_amdgcn_mfma_f32_16x16x32_bf16(a, bf, acc[t], 0, 0, 0);
        }
    }
#pragma unroll
    for (int t = 0; t < 4; ++t) {
        int gn = n0g + t * 16 + l16;
        if (gn < Nn) {
            uint2 u;
            u.x = packbf(acc[t][0], acc[t][1]);
            u.y = packbf(acc[t][2], acc[t][3]);
            *(uint2*)&h2t[((size_t)wave * Nn + gn) * 8 + quad * 2] = u;
        }
    }
}

// ---------- agg1: 8 chunks XCD-pinned, high-occupancy grid; wave=node, 8 groups x 8 lanes ----------
__global__ __launch_bounds__(256) void agg1_k(const unsigned* __restrict__ ht,
                                              const int* __restrict__ row_ptr,
                                              const int* __restrict__ cnt,
                                              const int* __restrict__ colv,
                                              const float* __restrict__ dinv,
                                              const float* __restrict__ bias,
                                              unsigned* __restrict__ outt, int Nn) {
    int c = blockIdx.x & 7;
    int bj = blockIdx.x >> 3;
    int NB = gridDim.x >> 3;
    int wave = threadIdx.x >> 6, lane = threadIdx.x & 63;
    int g = lane >> 3, f = lane & 7;
    const unsigned* hc = ht + (size_t)c * Nn * 8;
    unsigned* oc = outt + (size_t)c * Nn * 8;
    float b0 = bias[c * 16 + f * 2], b1 = bias[c * 16 + f * 2 + 1];
    for (int v = bj * 4 + wave; v < Nn; v += NB * 4) {
        float di = dinv[v];
        int start = row_ptr[v], end = start + cnt[v];
        float ax = 0.f, ay = 0.f;
        if (g == 0) {
            float2 hv = bfpair(hc[(size_t)v * 8 + f]);
            float w0 = di * di;
            ax = w0 * hv.x; ay = w0 * hv.y;
        }
        int e = start + g;
        for (; e + 8 < end; e += 16) {  // 2 independent chains per lane
            int s0 = __builtin_nontemporal_load(colv + e);
            int s1 = __builtin_nontemporal_load(colv + e + 8);
            float w0e = di * dinv[s0], w1e = di * dinv[s1];
            float2 v0 = bfpair(hc[(size_t)s0 * 8 + f]);
            float2 v1 = bfpair(hc[(size_t)s1 * 8 + f]);
            ax = fmaf(w0e, v0.x, ax); ay = fmaf(w0e, v0.y, ay);
            ax = fmaf(w1e, v1.x, ax); ay = fmaf(w1e, v1.y, ay);
        }
        if (e < end) {
            int s = __builtin_nontemporal_load(colv + e);
            float w = di * dinv[s];
            float2 hv = bfpair(hc[(size_t)s * 8 + f]);
            ax = fmaf(w, hv.x, ax); ay = fmaf(w, hv.y, ay);
        }
        ax += __shfl_xor(ax, 8, 64);  ay += __shfl_xor(ay, 8, 64);
        ax += __shfl_xor(ax, 16, 64); ay += __shfl_xor(ay, 16, 64);
        ax += __shfl_xor(ax, 32, 64); ay += __shfl_xor(ay, 32, 64);
        if (g == 0) {
            float r0 = fmaxf(ax + b0, 0.f);
            float r1 = fmaxf(ay + b1, 0.f);
            oc[(size_t)v * 8 + f] = packbf(r0, r1);
        }
    }
}

// ---------- agg2: 4 chunks x 2 node-halves; fp32 node-major out ----------
__global__ __launch_bounds__(256) void agg2_k(const unsigned* __restrict__ ht,
                                              const int* __restrict__ row_ptr,
                                              const int* __restrict__ cnt,
                                              const int* __restrict__ colv,
                                              const float* __restrict__ dinv,
                                              const float* __restrict__ bias,
                                              float* __restrict__ out, int Nn) {
    int xcd = blockIdx.x & 7;
    int c = xcd >> 1;
    int half = xcd & 1;
    int bj = blockIdx.x >> 3;
    int NB = gridDim.x >> 3;
    int wave = threadIdx.x >> 6, lane = threadIdx.x & 63;
    int g = lane >> 3, f = lane & 7;
    const unsigned* hc = ht + (size_t)c * Nn * 8;
    float b0 = bias[c * 16 + f * 2], b1 = bias[c * 16 + f * 2 + 1];
    int vlo = half * (Nn / 2), vhi = vlo + (Nn / 2) + (half ? (Nn & 1) : 0);
    for (int v = vlo + bj * 4 + wave; v < vhi; v += NB * 4) {
        float di = dinv[v];
        int start = row_ptr[v], end = start + cnt[v];
        float ax = 0.f, ay = 0.f;
        if (g == 0) {
            float2 hv = bfpair(hc[(size_t)v * 8 + f]);
            float w0 = di * di;
            ax = w0 * hv.x; ay = w0 * hv.y;
        }
        int e = start + g;
        for (; e + 8 < end; e += 16) {
            int s0 = __builtin_nontemporal_load(colv + e);
            int s1 = __builtin_nontemporal_load(colv + e + 8);
            float w0e = di * dinv[s0], w1e = di * dinv[s1];
            float2 v0 = bfpair(hc[(size_t)s0 * 8 + f]);
            float2 v1 = bfpair(hc[(size_t)s1 * 8 + f]);
            ax = fmaf(w0e, v0.x, ax); ay = fmaf(w0e, v0.y, ay);
            ax = fmaf(w1e, v1.x, ax); ay = fmaf(w1e, v1.y, ay);
        }
        if (e < end) {
            int s = __builtin_nontemporal_load(colv + e);
            float w = di * dinv[s];
            float2 hv = bfpair(hc[(size_t)s * 8 + f]);
            ax = fmaf(w, hv.x, ax); ay = fmaf(w, hv.y, ay);
        }
        ax += __shfl_xor(ax, 8, 64);  ay += __shfl_xor(ay, 8, 64);
        ax += __shfl_xor(ax, 16, 64); ay += __shfl_xor(ay, 16, 64);
        ax += __shfl_xor(ax, 32, 64); ay += __shfl_xor(ay, 32, 64);
        if (g == 0) {
            float2 r = make_float2(ax + b0, ay + b1);
            *(float2*)&out[(size_t)v * 64 + c * 16 + f * 2] = r;
        }
    }
}

// ---------- launch ----------
extern "C" void kernel_launch(void* const* d_in, const int* in_sizes, int n_in,
                              void* d_out, int out_size, void* d_ws, size_t ws_size,
                              hipStream_t stream) {
    const float* x  = (const float*)d_in[0];
    const void*  ei = d_in[1];
    const float* W1 = (const float*)d_in[2];
    const float* b1 = (const float*)d_in[3];
    const float* W2 = (const float*)d_in[4];
    const float* b2 = (const float*)d_in[5];

    const int N = N_NODES;
    const int E = in_sizes[1] / 2;

    char* w = (char*)d_ws;
    size_t off = 0;
    auto take = [&](size_t bytes) {
        void* p = w + off;
        off = (off + bytes + 255) & ~(size_t)255;
        return p;
    };
    int*   flag    = (int*)take(sizeof(int));
    int*   cnt     = (int*)take((size_t)N * 4);
    int*   row_ptr = (int*)take((size_t)N * 4);
    int*   pos     = (int*)take((size_t)N * 4);
    int*   bsum    = (int*)take(128 * 4);
    float* dinv    = (float*)take((size_t)N * 4);
    int*   esrc    = (int*)take((size_t)E * 4);
    int*   edst    = (int*)take((size_t)E * 4);
    int*   colv    = (int*)take((size_t)E * 4);
    unsigned short* w1bf = (unsigned short*)take(128 * 128 * 2);
    unsigned short* w2bf = (unsigned short*)take(64 * 128 * 2);
    unsigned* hrt  = (unsigned*)take((size_t)8 * N * 8 * 4);   // 25.6 MB
    unsigned* h2t  = (unsigned*)take((size_t)4 * N * 8 * 4);   // 12.8 MB
    (void)ws_size; (void)n_in; (void)out_size;

    unsigned* h1t = (unsigned*)d_out;  // 25.6 MB, dead before agg2's final write

    const int nscan = (N + 1023) / 1024;  // 98

    detect64_k<<<1, 64, 0, stream>>>((const unsigned long long*)ei, flag);
    convert_k<<<(E + 255) / 256, 256, 0, stream>>>(ei, flag, esrc, edst, E);
    zero_k<<<(N + 255) / 256, 256, 0, stream>>>(cnt, N);
    count_k<<<(E + 255) / 256, 256, 0, stream>>>(edst, cnt, E);
    scan1_k<<<nscan, 256, 0, stream>>>(cnt, row_ptr, bsum, N);
    scan2_k<<<1, 256, 0, stream>>>(bsum, nscan);
    scan3_k<<<nscan, 256, 0, stream>>>(bsum, cnt, row_ptr, pos, dinv, N);
    fill_stripe_k<<<1024, 256, 0, stream>>>(esrc, edst, pos, colv, E);
    prep_w_k<<<64, 256, 0, stream>>>(W1, W2, w1bf, w2bf);

    gemm1_k<<<(N + 63) / 64, 256, 0, stream>>>(x, w1bf, h1t, N);
    agg1_k<<<25000, 256, 0, stream>>>(h1t, row_ptr, cnt, colv, dinv, b1, hrt, N);
    gemm2_k<<<(N + 63) / 64, 256, 0, stream>>>(hrt, w2bf, h2t, N);
    agg2_k<<<25000, 256, 0, stream>>>(h2t, row_ptr, cnt, colv, dinv, b2, (float*)d_out, N);
}

// Round 7
// 623.014 us; speedup vs baseline: 9.6409x; 1.6464x over previous
//
#include <hip/hip_runtime.h>

// 2-layer GCN, R7: node-major single-pass aggregation with wave-batched
// colv/dinv loads (+shfl distribution) and 4-deep row-gather MLP.
// R6's chunk-major agg paid 8x redundant edge traversal and was latency-bound
// (VALUBusy 32%, HBM 4%). GEMMs are MFMA with LDS-transpose epilogue to emit
// node-major bf16. CSR build unchanged (R3-proven striped fill).

#define N_NODES 100000
#define STRIPE_SZ 12500  // 8 stripes

typedef __attribute__((ext_vector_type(8))) short short8;
typedef __attribute__((ext_vector_type(4))) float f32x4;

// ---------- bf16 helpers (RN-even) ----------
__device__ __forceinline__ unsigned short f2bf(float f) {
    union { float f; unsigned u; } c; c.f = f;
    unsigned r = (c.u + 0x7fffu + ((c.u >> 16) & 1u)) >> 16;
    return (unsigned short)r;
}
__device__ __forceinline__ float2 bfpair(unsigned u) {
    union { float f; unsigned u; } a, b;
    a.u = u << 16; b.u = u & 0xffff0000u;
    return make_float2(a.f, b.f);
}
__device__ __forceinline__ unsigned packbf(float a, float b) {
    return (unsigned)f2bf(a) | ((unsigned)f2bf(b) << 16);
}

// ---------- edge dtype detection (one wave) ----------
__global__ void detect64_k(const unsigned long long* __restrict__ ei, int* __restrict__ flag) {
    unsigned long long v = ei[threadIdx.x & 63];
    unsigned long long bad = __ballot(v >= (1ULL << 32));
    if (threadIdx.x == 0) *flag = (bad == 0ULL) ? 1 : 0;
}

__device__ __forceinline__ int edge_at(const void* ei, int is64, long long idx) {
    if (is64) return (int)((const long long*)ei)[idx];
    return ((const int*)ei)[idx];
}

// ---------- convert edge_index -> int32 src/dst ----------
__global__ void convert_k(const void* __restrict__ ei, const int* __restrict__ flag,
                          int* __restrict__ esrc, int* __restrict__ edst, int E) {
    int e = blockIdx.x * blockDim.x + threadIdx.x;
    if (e >= E) return;
    int is64 = *flag;
    esrc[e] = edge_at(ei, is64, e);
    edst[e] = edge_at(ei, is64, (long long)E + e);
}

__global__ void zero_k(int* __restrict__ p, int n) {
    int i = blockIdx.x * blockDim.x + threadIdx.x;
    if (i < n) p[i] = 0;
}

// ---------- degree count ----------
__global__ void count_k(const int* __restrict__ edst, int* __restrict__ cnt, int E) {
    int e = blockIdx.x * blockDim.x + threadIdx.x;
    if (e >= E) return;
    int d = edst[e];
    if ((unsigned)d < (unsigned)N_NODES) atomicAdd(&cnt[d], 1);
}

// ---------- exclusive scan, 1024 elems/block ----------
__global__ void scan1_k(const int* __restrict__ cnt, int* __restrict__ partial,
                        int* __restrict__ bsum, int n) {
    __shared__ int sm[256];
    int t = threadIdx.x;
    int base = blockIdx.x * 1024 + t * 4;
    int v[4]; int loc = 0;
#pragma unroll
    for (int j = 0; j < 4; ++j) { v[j] = (base + j < n) ? cnt[base + j] : 0; loc += v[j]; }
    sm[t] = loc; __syncthreads();
    for (int off = 1; off < 256; off <<= 1) {
        int x = (t >= off) ? sm[t - off] : 0;
        __syncthreads();
        sm[t] += x;
        __syncthreads();
    }
    int incl = sm[t];
    int run = incl - loc;
    if (t == 255) bsum[blockIdx.x] = incl;
#pragma unroll
    for (int j = 0; j < 4; ++j) {
        if (base + j < n) partial[base + j] = run;
        run += v[j];
    }
}

__global__ void scan2_k(int* __restrict__ bsum, int nb) {
    __shared__ int sm[256];
    int t = threadIdx.x;
    int v = (t < nb) ? bsum[t] : 0;
    sm[t] = v; __syncthreads();
    for (int off = 1; off < 256; off <<= 1) {
        int x = (t >= off) ? sm[t - off] : 0;
        __syncthreads();
        sm[t] += x;
        __syncthreads();
    }
    if (t < nb) bsum[t] = sm[t] - v;
}

__global__ void scan3_k(const int* __restrict__ bsum, const int* __restrict__ cnt,
                        int* __restrict__ row_ptr, int* __restrict__ pos,
                        float* __restrict__ dinv, int n) {
    int base = blockIdx.x * 1024 + threadIdx.x * 4;
    int add = bsum[blockIdx.x];
#pragma unroll
    for (int j = 0; j < 4; ++j) {
        int i = base + j;
        if (i < n) {
            int r = row_ptr[i] + add;
            row_ptr[i] = r;
            pos[i] = r;
            dinv[i] = rsqrtf((float)(cnt[i] + 1));  // +1 self-loop
        }
    }
}

// ---------- striped CSR fill ----------
__global__ __launch_bounds__(256) void fill_stripe_k(const int* __restrict__ esrc,
                                                     const int* __restrict__ edst,
                                                     int* __restrict__ pos,
                                                     int* __restrict__ colv, int E) {
    int stride = gridDim.x * blockDim.x;
    int tid = blockIdx.x * blockDim.x + threadIdx.x;
    for (int s = 0; s < 8; ++s) {
        for (int e = tid; e < E; e += stride) {
            int d = edst[e];
            if ((unsigned)d >= (unsigned)N_NODES) continue;
            if (d / STRIPE_SZ != s) continue;
            int sv = esrc[e];
            int slot = atomicAdd(&pos[d], 1);
            colv[slot] = sv;
        }
    }
}

// ---------- weight prep: W^T in bf16 ----------
__global__ void prep_w_k(const float* __restrict__ W1, const float* __restrict__ W2,
                         unsigned short* __restrict__ w1bf, unsigned short* __restrict__ w2bf) {
    int i = blockIdx.x * 256 + threadIdx.x;
    if (i < 128 * 128) { int k = i >> 7, f = i & 127; w1bf[f * 128 + k] = f2bf(W1[i]); }
    if (i < 128 * 64)  { int k = i >> 6, f = i & 63;  w2bf[f * 128 + k] = f2bf(W2[i]); }
}

// ---------- GEMM1 (MFMA): h1[n][128] bf16 node-major = x @ W1 ----------
__global__ __launch_bounds__(256) void gemm1_k(const float* __restrict__ x,
                                               const unsigned short* __restrict__ w1bf,
                                               unsigned* __restrict__ h1, int Nn) {
    __shared__ __align__(16) unsigned short sA[128][136];  // W1^T [feat][k]
    __shared__ __align__(16) unsigned short sB[64][136];   // x [node][k] bf16
    int tid = threadIdx.x;
    int n0g = blockIdx.x * 64;
    {   // stage A: 2048 uint4, 8/thread
        const uint4* src = (const uint4*)w1bf;
#pragma unroll
        for (int l = 0; l < 8; ++l) {
            int idx = tid + l * 256;
            int f = idx >> 4, kq = idx & 15;
            *(uint4*)&sA[f][kq * 8] = src[idx];
        }
    }
    {   // stage B: node rows fp32 -> bf16
        int n = tid >> 2, kq = tid & 3;
        int gn = n0g + n; if (gn >= Nn) gn = Nn - 1;
        const float4* xr = (const float4*)(x + (size_t)gn * 128 + kq * 32);
        unsigned short* dst = &sB[n][kq * 32];
#pragma unroll
        for (int i = 0; i < 8; ++i) {
            float4 v = xr[i];
            dst[i * 4 + 0] = f2bf(v.x); dst[i * 4 + 1] = f2bf(v.y);
            dst[i * 4 + 2] = f2bf(v.z); dst[i * 4 + 3] = f2bf(v.w);
        }
    }
    __syncthreads();
    int wave = tid >> 6, lane = tid & 63;
    int quad = lane >> 4, l16 = lane & 15;
    f32x4 z = {0.f, 0.f, 0.f, 0.f};
    f32x4 acc[8];
#pragma unroll
    for (int t = 0; t < 8; ++t) acc[t] = z;
    // A = x rows (m=node), B = W^T rows (n=feat): D[m=node][n=feat]
#pragma unroll
    for (int kk = 0; kk < 4; ++kk) {
        int kb = kk * 32 + quad * 8;
        short8 a = *(const short8*)&sB[wave * 16 + l16][kb];
#pragma unroll
        for (int ft = 0; ft < 8; ++ft) {
            short8 b = *(const short8*)&sA[ft * 16 + l16][kb];
            acc[ft] = __builtin_amdgcn_mfma_f32_16x16x32_bf16(a, b, acc[ft], 0, 0, 0);
        }
    }
    __syncthreads();  // all LDS reads done; reuse sA as transpose buffer
    unsigned short (*sC)[136] = sA;  // 64 rows x 128 feats used
#pragma unroll
    for (int ft = 0; ft < 8; ++ft)
#pragma unroll
        for (int r = 0; r < 4; ++r)
            sC[wave * 16 + quad * 4 + r][ft * 16 + l16] = f2bf(acc[ft][r]);
    __syncthreads();
#pragma unroll
    for (int l = 0; l < 4; ++l) {   // 64 rows x 16 uint4
        int idx = tid + l * 256;
        int row = idx >> 4, q = idx & 15;
        int gn = n0g + row;
        if (gn < Nn)
            *(uint4*)&h1[(size_t)gn * 64 + q * 4] = *(uint4*)&sC[row][q * 8];
    }
}

// ---------- GEMM2 (MFMA): h2[n][64] bf16 node-major = hr @ W2 ----------
__global__ __launch_bounds__(256) void gemm2_k(const unsigned* __restrict__ hr,  // [N][64] uints
                                               const unsigned short* __restrict__ w2bf,
                                               unsigned* __restrict__ h2, int Nn) {
    __shared__ __align__(16) unsigned short sA[64][136];  // W2^T [feat][k]
    __shared__ __align__(16) unsigned short sB[64][136];  // hr [node][k] bf16
    int tid = threadIdx.x;
    int n0g = blockIdx.x * 64;
    {   // stage A: 1024 uint4, 4/thread
        const uint4* src = (const uint4*)w2bf;
#pragma unroll
        for (int l = 0; l < 4; ++l) {
            int idx = tid + l * 256;
            int f = idx >> 4, kq = idx & 15;
            *(uint4*)&sA[f][kq * 8] = src[idx];
        }
    }
    {   // stage B: 1024 uint4 from node-major hr
        const uint4* src = (const uint4*)hr;
#pragma unroll
        for (int l = 0; l < 4; ++l) {
            int idx = tid + l * 256;
            int row = idx >> 4, q = idx & 15;
            int gn = n0g + row; if (gn >= Nn) gn = Nn - 1;
            *(uint4*)&sB[row][q * 8] = src[(size_t)gn * 16 + q];
        }
    }
    __syncthreads();
    int wave = tid >> 6, lane = tid & 63;
    int quad = lane >> 4, l16 = lane & 15;
    f32x4 z = {0.f, 0.f, 0.f, 0.f};
    f32x4 acc[4];
#pragma unroll
    for (int t = 0; t < 4; ++t) acc[t] = z;
#pragma unroll
    for (int kk = 0; kk < 4; ++kk) {
        int kb = kk * 32 + quad * 8;
        short8 a = *(const short8*)&sB[wave * 16 + l16][kb];
#pragma unroll
        for (int ft = 0; ft < 4; ++ft) {
            short8 b = *(const short8*)&sA[ft * 16 + l16][kb];
            acc[ft] = __builtin_amdgcn_mfma_f32_16x16x32_bf16(a, b, acc[ft], 0, 0, 0);
        }
    }
    __syncthreads();
    unsigned short (*sC)[136] = sA;  // 64 rows x 64 feats used
#pragma unroll
    for (int ft = 0; ft < 4; ++ft)
#pragma unroll
        for (int r = 0; r < 4; ++r)
            sC[wave * 16 + quad * 4 + r][ft * 16 + l16] = f2bf(acc[ft][r]);
    __syncthreads();
#pragma unroll
    for (int l = 0; l < 2; ++l) {   // 64 rows x 8 uint4
        int idx = tid + l * 256;
        int row = idx >> 3, q = idx & 7;
        int gn = n0g + row;
        if (gn < Nn)
            *(uint4*)&h2[(size_t)gn * 32 + q * 4] = *(uint4*)&sC[row][q * 8];
    }
}

// ---------- agg1: wave=node, batched colv/dinv + shfl, 4-deep row-gather MLP ----------
__global__ __launch_bounds__(256) void agg1_k(const unsigned* __restrict__ h,  // [N][64] uints
                                              const int* __restrict__ row_ptr,
                                              const int* __restrict__ cnt,
                                              const int* __restrict__ colv,
                                              const float* __restrict__ dinv,
                                              const float* __restrict__ bias,
                                              unsigned* __restrict__ out, int Nn, int E) {
    int node = blockIdx.x * 4 + (threadIdx.x >> 6);
    if (node >= Nn) return;
    int lane = threadIdx.x & 63;
    float di = dinv[node];
    int start = row_ptr[node];
    int deg = cnt[node];

    float2 hv = bfpair(h[(size_t)node * 64 + lane]);
    float w0 = di * di;
    float ax = w0 * hv.x, ay = w0 * hv.y;

    for (int base = 0; base < deg; base += 64) {
        int idx = base + lane;
        int ci = start + idx; if (ci >= E) ci = E - 1;     // clamp; masked via wl
        int sl = colv[ci];
        float wl = (idx < deg) ? dinv[sl] : 0.f;           // lanes >= m carry w=0
        int m = deg - base; if (m > 64) m = 64;
        int j = 0;
        for (; j + 4 <= m; j += 4) {
            int s0 = __shfl(sl, j),     s1 = __shfl(sl, j + 1);
            int s2 = __shfl(sl, j + 2), s3 = __shfl(sl, j + 3);
            float e0 = di * __shfl(wl, j),     e1 = di * __shfl(wl, j + 1);
            float e2 = di * __shfl(wl, j + 2), e3 = di * __shfl(wl, j + 3);
            unsigned u0 = h[(size_t)s0 * 64 + lane];
            unsigned u1 = h[(size_t)s1 * 64 + lane];
            unsigned u2 = h[(size_t)s2 * 64 + lane];
            unsigned u3 = h[(size_t)s3 * 64 + lane];
            float2 v0 = bfpair(u0), v1 = bfpair(u1), v2 = bfpair(u2), v3 = bfpair(u3);
            ax = fmaf(e0, v0.x, ax); ay = fmaf(e0, v0.y, ay);
            ax = fmaf(e1, v1.x, ax); ay = fmaf(e1, v1.y, ay);
            ax = fmaf(e2, v2.x, ax); ay = fmaf(e2, v2.y, ay);
            ax = fmaf(e3, v3.x, ax); ay = fmaf(e3, v3.y, ay);
        }
        for (; j < m; ++j) {
            int s = __shfl(sl, j);
            float we = di * __shfl(wl, j);
            float2 v = bfpair(h[(size_t)s * 64 + lane]);
            ax = fmaf(we, v.x, ax); ay = fmaf(we, v.y, ay);
        }
    }
    float r0 = fmaxf(ax + bias[lane * 2], 0.f);
    float r1 = fmaxf(ay + bias[lane * 2 + 1], 0.f);
    out[(size_t)node * 64 + lane] = packbf(r0, r1);
}

// ---------- agg2: wave=node, 2 edges per gather instruction (128 B rows) ----------
__global__ __launch_bounds__(256) void agg2_k(const unsigned* __restrict__ h,  // [N][32] uints
                                              const int* __restrict__ row_ptr,
                                              const int* __restrict__ cnt,
                                              const int* __restrict__ colv,
                                              const float* __restrict__ dinv,
                                              const float* __restrict__ bias,
                                              float* __restrict__ out, int Nn, int E) {
    int node = blockIdx.x * 4 + (threadIdx.x >> 6);
    if (node >= Nn) return;
    int lane = threadIdx.x & 63;
    int half = lane >> 5, fp = lane & 31;
    float di = dinv[node];
    int start = row_ptr[node];
    int deg = cnt[node];

    float2 hv = bfpair(h[(size_t)node * 32 + fp]);
    float w0 = (half == 0) ? di * di : 0.f;
    float ax = w0 * hv.x, ay = w0 * hv.y;

    for (int base = 0; base < deg; base += 64) {
        int idx = base + lane;
        int ci = start + idx; if (ci >= E) ci = E - 1;
        int sl = colv[ci];
        float wl = (idx < deg) ? dinv[sl] : 0.f;
        int m = deg - base; if (m > 64) m = 64;
        int j = 0;
        for (; j + 8 <= m; j += 8) {
            int q0 = j + half, q1 = j + 2 + half, q2 = j + 4 + half, q3 = j + 6 + half;
            int s0 = __shfl(sl, q0), s1 = __shfl(sl, q1);
            int s2 = __shfl(sl, q2), s3 = __shfl(sl, q3);
            float e0 = di * __shfl(wl, q0), e1 = di * __shfl(wl, q1);
            float e2 = di * __shfl(wl, q2), e3 = di * __shfl(wl, q3);
            unsigned u0 = h[(size_t)s0 * 32 + fp];
            unsigned u1 = h[(size_t)s1 * 32 + fp];
            unsigned u2 = h[(size_t)s2 * 32 + fp];
            unsigned u3 = h[(size_t)s3 * 32 + fp];
            float2 v0 = bfpair(u0), v1 = bfpair(u1), v2 = bfpair(u2), v3 = bfpair(u3);
            ax = fmaf(e0, v0.x, ax); ay = fmaf(e0, v0.y, ay);
            ax = fmaf(e1, v1.x, ax); ay = fmaf(e1, v1.y, ay);
            ax = fmaf(e2, v2.x, ax); ay = fmaf(e2, v2.y, ay);
            ax = fmaf(e3, v3.x, ax); ay = fmaf(e3, v3.y, ay);
        }
        for (; j < m; j += 2) {
            int q = j + half;                 // q may reach m..m+1: wl there is 0
            int s = __shfl(sl, q & 63);
            float we = di * __shfl(wl, q & 63);
            float2 v = bfpair(h[(size_t)s * 32 + fp]);
            ax = fmaf(we, v.x, ax); ay = fmaf(we, v.y, ay);
        }
    }
    ax += __shfl_xor(ax, 32, 64);
    ay += __shfl_xor(ay, 32, 64);
    if (half == 0) {
        float2 r = make_float2(ax + bias[fp * 2], ay + bias[fp * 2 + 1]);
        *(float2*)&out[(size_t)node * 64 + fp * 2] = r;
    }
}

// ---------- launch ----------
extern "C" void kernel_launch(void* const* d_in, const int* in_sizes, int n_in,
                              void* d_out, int out_size, void* d_ws, size_t ws_size,
                              hipStream_t stream) {
    const float* x  = (const float*)d_in[0];
    const void*  ei = d_in[1];
    const float* W1 = (const float*)d_in[2];
    const float* b1 = (const float*)d_in[3];
    const float* W2 = (const float*)d_in[4];
    const float* b2 = (const float*)d_in[5];

    const int N = N_NODES;
    const int E = in_sizes[1] / 2;

    char* w = (char*)d_ws;
    size_t off = 0;
    auto take = [&](size_t bytes) {
        void* p = w + off;
        off = (off + bytes + 255) & ~(size_t)255;
        return p;
    };
    int*   flag    = (int*)take(sizeof(int));
    int*   cnt     = (int*)take((size_t)N * 4);
    int*   row_ptr = (int*)take((size_t)N * 4);
    int*   pos     = (int*)take((size_t)N * 4);
    int*   bsum    = (int*)take(128 * 4);
    float* dinv    = (float*)take((size_t)N * 4);
    int*   esrc    = (int*)take((size_t)E * 4);
    int*   edst    = (int*)take((size_t)E * 4);
    int*   colv    = (int*)take((size_t)E * 4);
    unsigned short* w1bf = (unsigned short*)take(128 * 128 * 2);
    unsigned short* w2bf = (unsigned short*)take(64 * 128 * 2);
    unsigned* hr   = (unsigned*)take((size_t)N * 64 * 4);   // bf16 [N][128], 25.6 MB
    unsigned* h2   = (unsigned*)take((size_t)N * 32 * 4);   // bf16 [N][64], 12.8 MB
    (void)ws_size; (void)n_in; (void)out_size;

    unsigned* h1 = (unsigned*)d_out;  // bf16 [N][128] in d_out, dead before agg2 writes

    const int nscan = (N + 1023) / 1024;  // 98

    detect64_k<<<1, 64, 0, stream>>>((const unsigned long long*)ei, flag);
    convert_k<<<(E + 255) / 256, 256, 0, stream>>>(ei, flag, esrc, edst, E);
    zero_k<<<(N + 255) / 256, 256, 0, stream>>>(cnt, N);
    count_k<<<(E + 255) / 256, 256, 0, stream>>>(edst, cnt, E);
    scan1_k<<<nscan, 256, 0, stream>>>(cnt, row_ptr, bsum, N);
    scan2_k<<<1, 256, 0, stream>>>(bsum, nscan);
    scan3_k<<<nscan, 256, 0, stream>>>(bsum, cnt, row_ptr, pos, dinv, N);
    fill_stripe_k<<<1024, 256, 0, stream>>>(esrc, edst, pos, colv, E);
    prep_w_k<<<64, 256, 0, stream>>>(W1, W2, w1bf, w2bf);

    gemm1_k<<<(N + 63) / 64, 256, 0, stream>>>(x, w1bf, h1, N);
    agg1_k<<<(N + 3) / 4, 256, 0, stream>>>(h1, row_ptr, cnt, colv, dinv, b1, hr, N, E);
    gemm2_k<<<(N + 63) / 64, 256, 0, stream>>>(hr, w2bf, h2, N);
    agg2_k<<<(N + 3) / 4, 256, 0, stream>>>(h2, row_ptr, cnt, colv, dinv, b2, (float*)d_out, N, E);
}

// Round 8
// 580.066 us; speedup vs baseline: 10.3547x; 1.0740x over previous
//
#include <hip/hip_runtime.h>

// 2-layer GCN, R8: R7 + spatially XCD-pinned CSR fill (blockIdx&7 = stripe ->
// one XCD owns each stripe's pos/colv region; kills the 15x cross-XCD
// partial-line writeback seen in R7's temporal fill: WRITE 195MB for 12.8MB),
// and count fused into convert. Agg/GEMM unchanged from R7.

#define N_NODES 100000
#define STRIPE_SZ 12500  // 8 stripes exactly (8*12500 = 100000)

typedef __attribute__((ext_vector_type(8))) short short8;
typedef __attribute__((ext_vector_type(4))) float f32x4;

// ---------- bf16 helpers (RN-even) ----------
__device__ __forceinline__ unsigned short f2bf(float f) {
    union { float f; unsigned u; } c; c.f = f;
    unsigned r = (c.u + 0x7fffu + ((c.u >> 16) & 1u)) >> 16;
    return (unsigned short)r;
}
__device__ __forceinline__ float2 bfpair(unsigned u) {
    union { float f; unsigned u; } a, b;
    a.u = u << 16; b.u = u & 0xffff0000u;
    return make_float2(a.f, b.f);
}
__device__ __forceinline__ unsigned packbf(float a, float b) {
    return (unsigned)f2bf(a) | ((unsigned)f2bf(b) << 16);
}

// ---------- edge dtype detection (one wave) ----------
__global__ void detect64_k(const unsigned long long* __restrict__ ei, int* __restrict__ flag) {
    unsigned long long v = ei[threadIdx.x & 63];
    unsigned long long bad = __ballot(v >= (1ULL << 32));
    if (threadIdx.x == 0) *flag = (bad == 0ULL) ? 1 : 0;
}

__device__ __forceinline__ int edge_at(const void* ei, int is64, long long idx) {
    if (is64) return (int)((const long long*)ei)[idx];
    return ((const int*)ei)[idx];
}

// ---------- convert edge_index -> int32 src/dst + degree count (fused) ----------
__global__ void convcount_k(const void* __restrict__ ei, const int* __restrict__ flag,
                            int* __restrict__ esrc, int* __restrict__ edst,
                            int* __restrict__ cnt, int E) {
    int e = blockIdx.x * blockDim.x + threadIdx.x;
    if (e >= E) return;
    int is64 = *flag;
    int s = edge_at(ei, is64, e);
    int d = edge_at(ei, is64, (long long)E + e);
    esrc[e] = s;
    edst[e] = d;
    if ((unsigned)d < (unsigned)N_NODES) atomicAdd(&cnt[d], 1);
}

__global__ void zero_k(int* __restrict__ p, int n) {
    int i = blockIdx.x * blockDim.x + threadIdx.x;
    if (i < n) p[i] = 0;
}

// ---------- exclusive scan, 1024 elems/block ----------
__global__ void scan1_k(const int* __restrict__ cnt, int* __restrict__ partial,
                        int* __restrict__ bsum, int n) {
    __shared__ int sm[256];
    int t = threadIdx.x;
    int base = blockIdx.x * 1024 + t * 4;
    int v[4]; int loc = 0;
#pragma unroll
    for (int j = 0; j < 4; ++j) { v[j] = (base + j < n) ? cnt[base + j] : 0; loc += v[j]; }
    sm[t] = loc; __syncthreads();
    for (int off = 1; off < 256; off <<= 1) {
        int x = (t >= off) ? sm[t - off] : 0;
        __syncthreads();
        sm[t] += x;
        __syncthreads();
    }
    int incl = sm[t];
    int run = incl - loc;
    if (t == 255) bsum[blockIdx.x] = incl;
#pragma unroll
    for (int j = 0; j < 4; ++j) {
        if (base + j < n) partial[base + j] = run;
        run += v[j];
    }
}

__global__ void scan2_k(int* __restrict__ bsum, int nb) {
    __shared__ int sm[256];
    int t = threadIdx.x;
    int v = (t < nb) ? bsum[t] : 0;
    sm[t] = v; __syncthreads();
    for (int off = 1; off < 256; off <<= 1) {
        int x = (t >= off) ? sm[t - off] : 0;
        __syncthreads();
        sm[t] += x;
        __syncthreads();
    }
    if (t < nb) bsum[t] = sm[t] - v;
}

__global__ void scan3_k(const int* __restrict__ bsum, const int* __restrict__ cnt,
                        int* __restrict__ row_ptr, int* __restrict__ pos,
                        float* __restrict__ dinv, int n) {
    int base = blockIdx.x * 1024 + threadIdx.x * 4;
    int add = bsum[blockIdx.x];
#pragma unroll
    for (int j = 0; j < 4; ++j) {
        int i = base + j;
        if (i < n) {
            int r = row_ptr[i] + add;
            row_ptr[i] = r;
            pos[i] = r;
            dinv[i] = rsqrtf((float)(cnt[i] + 1));  // +1 self-loop
        }
    }
}

// ---------- XCD-pinned CSR fill: blockIdx&7 = stripe; pos/colv region single-XCD ----------
__global__ __launch_bounds__(256) void fill_xcd_k(const int* __restrict__ esrc,
                                                  const int* __restrict__ edst,
                                                  int* __restrict__ pos,
                                                  int* __restrict__ colv, int E) {
    int s = blockIdx.x & 7;
    int j = blockIdx.x >> 3;
    int NB = gridDim.x >> 3;
    int lo = s * STRIPE_SZ, hi = lo + STRIPE_SZ;
    for (int e = j * 256 + threadIdx.x; e < E; e += NB * 256) {
        int d = edst[e];
        if (d < lo || d >= hi) continue;  // also drops invalid ids
        int slot = atomicAdd(&pos[d], 1);
        colv[slot] = esrc[e];
    }
}

// ---------- weight prep: W^T in bf16 ----------
__global__ void prep_w_k(const float* __restrict__ W1, const float* __restrict__ W2,
                         unsigned short* __restrict__ w1bf, unsigned short* __restrict__ w2bf) {
    int i = blockIdx.x * 256 + threadIdx.x;
    if (i < 128 * 128) { int k = i >> 7, f = i & 127; w1bf[f * 128 + k] = f2bf(W1[i]); }
    if (i < 128 * 64)  { int k = i >> 6, f = i & 63;  w2bf[f * 128 + k] = f2bf(W2[i]); }
}

// ---------- GEMM1 (MFMA): h1[n][128] bf16 node-major = x @ W1 ----------
__global__ __launch_bounds__(256) void gemm1_k(const float* __restrict__ x,
                                               const unsigned short* __restrict__ w1bf,
                                               unsigned* __restrict__ h1, int Nn) {
    __shared__ __align__(16) unsigned short sA[128][136];  // W1^T [feat][k]
    __shared__ __align__(16) unsigned short sB[64][136];   // x [node][k] bf16
    int tid = threadIdx.x;
    int n0g = blockIdx.x * 64;
    {   // stage A: 2048 uint4, 8/thread
        const uint4* src = (const uint4*)w1bf;
#pragma unroll
        for (int l = 0; l < 8; ++l) {
            int idx = tid + l * 256;
            int f = idx >> 4, kq = idx & 15;
            *(uint4*)&sA[f][kq * 8] = src[idx];
        }
    }
    {   // stage B: node rows fp32 -> bf16
        int n = tid >> 2, kq = tid & 3;
        int gn = n0g + n; if (gn >= Nn) gn = Nn - 1;
        const float4* xr = (const float4*)(x + (size_t)gn * 128 + kq * 32);
        unsigned short* dst = &sB[n][kq * 32];
#pragma unroll
        for (int i = 0; i < 8; ++i) {
            float4 v = xr[i];
            dst[i * 4 + 0] = f2bf(v.x); dst[i * 4 + 1] = f2bf(v.y);
            dst[i * 4 + 2] = f2bf(v.z); dst[i * 4 + 3] = f2bf(v.w);
        }
    }
    __syncthreads();
    int wave = tid >> 6, lane = tid & 63;
    int quad = lane >> 4, l16 = lane & 15;
    f32x4 z = {0.f, 0.f, 0.f, 0.f};
    f32x4 acc[8];
#pragma unroll
    for (int t = 0; t < 8; ++t) acc[t] = z;
#pragma unroll
    for (int kk = 0; kk < 4; ++kk) {
        int kb = kk * 32 + quad * 8;
        short8 a = *(const short8*)&sB[wave * 16 + l16][kb];
#pragma unroll
        for (int ft = 0; ft < 8; ++ft) {
            short8 b = *(const short8*)&sA[ft * 16 + l16][kb];
            acc[ft] = __builtin_amdgcn_mfma_f32_16x16x32_bf16(a, b, acc[ft], 0, 0, 0);
        }
    }
    __syncthreads();  // reuse sA as transpose buffer
    unsigned short (*sC)[136] = sA;
#pragma unroll
    for (int ft = 0; ft < 8; ++ft)
#pragma unroll
        for (int r = 0; r < 4; ++r)
            sC[wave * 16 + quad * 4 + r][ft * 16 + l16] = f2bf(acc[ft][r]);
    __syncthreads();
#pragma unroll
    for (int l = 0; l < 4; ++l) {
        int idx = tid + l * 256;
        int row = idx >> 4, q = idx & 15;
        int gn = n0g + row;
        if (gn < Nn)
            *(uint4*)&h1[(size_t)gn * 64 + q * 4] = *(uint4*)&sC[row][q * 8];
    }
}

// ---------- GEMM2 (MFMA): h2[n][64] bf16 node-major = hr @ W2 ----------
__global__ __launch_bounds__(256) void gemm2_k(const unsigned* __restrict__ hr,
                                               const unsigned short* __restrict__ w2bf,
                                               unsigned* __restrict__ h2, int Nn) {
    __shared__ __align__(16) unsigned short sA[64][136];
    __shared__ __align__(16) unsigned short sB[64][136];
    int tid = threadIdx.x;
    int n0g = blockIdx.x * 64;
    {
        const uint4* src = (const uint4*)w2bf;
#pragma unroll
        for (int l = 0; l < 4; ++l) {
            int idx = tid + l * 256;
            int f = idx >> 4, kq = idx & 15;
            *(uint4*)&sA[f][kq * 8] = src[idx];
        }
    }
    {
        const uint4* src = (const uint4*)hr;
#pragma unroll
        for (int l = 0; l < 4; ++l) {
            int idx = tid + l * 256;
            int row = idx >> 4, q = idx & 15;
            int gn = n0g + row; if (gn >= Nn) gn = Nn - 1;
            *(uint4*)&sB[row][q * 8] = src[(size_t)gn * 16 + q];
        }
    }
    __syncthreads();
    int wave = tid >> 6, lane = tid & 63;
    int quad = lane >> 4, l16 = lane & 15;
    f32x4 z = {0.f, 0.f, 0.f, 0.f};
    f32x4 acc[4];
#pragma unroll
    for (int t = 0; t < 4; ++t) acc[t] = z;
#pragma unroll
    for (int kk = 0; kk < 4; ++kk) {
        int kb = kk * 32 + quad * 8;
        short8 a = *(const short8*)&sB[wave * 16 + l16][kb];
#pragma unroll
        for (int ft = 0; ft < 4; ++ft) {
            short8 b = *(const short8*)&sA[ft * 16 + l16][kb];
            acc[ft] = __builtin_amdgcn_mfma_f32_16x16x32_bf16(a, b, acc[ft], 0, 0, 0);
        }
    }
    __syncthreads();
    unsigned short (*sC)[136] = sA;
#pragma unroll
    for (int ft = 0; ft < 4; ++ft)
#pragma unroll
        for (int r = 0; r < 4; ++r)
            sC[wave * 16 + quad * 4 + r][ft * 16 + l16] = f2bf(acc[ft][r]);
    __syncthreads();
#pragma unroll
    for (int l = 0; l < 2; ++l) {
        int idx = tid + l * 256;
        int row = idx >> 3, q = idx & 7;
        int gn = n0g + row;
        if (gn < Nn)
            *(uint4*)&h2[(size_t)gn * 32 + q * 4] = *(uint4*)&sC[row][q * 8];
    }
}

// ---------- agg1: wave=node, batched colv/dinv + shfl, 4-deep row-gather MLP ----------
__global__ __launch_bounds__(256) void agg1_k(const unsigned* __restrict__ h,
                                              const int* __restrict__ row_ptr,
                                              const int* __restrict__ cnt,
                                              const int* __restrict__ colv,
                                              const float* __restrict__ dinv,
                                              const float* __restrict__ bias,
                                              unsigned* __restrict__ out, int Nn, int E) {
    int node = blockIdx.x * 4 + (threadIdx.x >> 6);
    if (node >= Nn) return;
    int lane = threadIdx.x & 63;
    float di = dinv[node];
    int start = row_ptr[node];
    int deg = cnt[node];

    float2 hv = bfpair(h[(size_t)node * 64 + lane]);
    float w0 = di * di;
    float ax = w0 * hv.x, ay = w0 * hv.y;

    for (int base = 0; base < deg; base += 64) {
        int idx = base + lane;
        int ci = start + idx; if (ci >= E) ci = E - 1;
        int sl = colv[ci];
        float wl = (idx < deg) ? dinv[sl] : 0.f;
        int m = deg - base; if (m > 64) m = 64;
        int j = 0;
        for (; j + 4 <= m; j += 4) {
            int s0 = __shfl(sl, j),     s1 = __shfl(sl, j + 1);
            int s2 = __shfl(sl, j + 2), s3 = __shfl(sl, j + 3);
            float e0 = di * __shfl(wl, j),     e1 = di * __shfl(wl, j + 1);
            float e2 = di * __shfl(wl, j + 2), e3 = di * __shfl(wl, j + 3);
            unsigned u0 = h[(size_t)s0 * 64 + lane];
            unsigned u1 = h[(size_t)s1 * 64 + lane];
            unsigned u2 = h[(size_t)s2 * 64 + lane];
            unsigned u3 = h[(size_t)s3 * 64 + lane];
            float2 v0 = bfpair(u0), v1 = bfpair(u1), v2 = bfpair(u2), v3 = bfpair(u3);
            ax = fmaf(e0, v0.x, ax); ay = fmaf(e0, v0.y, ay);
            ax = fmaf(e1, v1.x, ax); ay = fmaf(e1, v1.y, ay);
            ax = fmaf(e2, v2.x, ax); ay = fmaf(e2, v2.y, ay);
            ax = fmaf(e3, v3.x, ax); ay = fmaf(e3, v3.y, ay);
        }
        for (; j < m; ++j) {
            int s = __shfl(sl, j);
            float we = di * __shfl(wl, j);
            float2 v = bfpair(h[(size_t)s * 64 + lane]);
            ax = fmaf(we, v.x, ax); ay = fmaf(we, v.y, ay);
        }
    }
    float r0 = fmaxf(ax + bias[lane * 2], 0.f);
    float r1 = fmaxf(ay + bias[lane * 2 + 1], 0.f);
    out[(size_t)node * 64 + lane] = packbf(r0, r1);
}

// ---------- agg2: wave=node, 2 edges per gather instruction ----------
__global__ __launch_bounds__(256) void agg2_k(const unsigned* __restrict__ h,
                                              const int* __restrict__ row_ptr,
                                              const int* __restrict__ cnt,
                                              const int* __restrict__ colv,
                                              const float* __restrict__ dinv,
                                              const float* __restrict__ bias,
                                              float* __restrict__ out, int Nn, int E) {
    int node = blockIdx.x * 4 + (threadIdx.x >> 6);
    if (node >= Nn) return;
    int lane = threadIdx.x & 63;
    int half = lane >> 5, fp = lane & 31;
    float di = dinv[node];
    int start = row_ptr[node];
    int deg = cnt[node];

    float2 hv = bfpair(h[(size_t)node * 32 + fp]);
    float w0 = (half == 0) ? di * di : 0.f;
    float ax = w0 * hv.x, ay = w0 * hv.y;

    for (int base = 0; base < deg; base += 64) {
        int idx = base + lane;
        int ci = start + idx; if (ci >= E) ci = E - 1;
        int sl = colv[ci];
        float wl = (idx < deg) ? dinv[sl] : 0.f;
        int m = deg - base; if (m > 64) m = 64;
        int j = 0;
        for (; j + 8 <= m; j += 8) {
            int q0 = j + half, q1 = j + 2 + half, q2 = j + 4 + half, q3 = j + 6 + half;
            int s0 = __shfl(sl, q0), s1 = __shfl(sl, q1);
            int s2 = __shfl(sl, q2), s3 = __shfl(sl, q3);
            float e0 = di * __shfl(wl, q0), e1 = di * __shfl(wl, q1);
            float e2 = di * __shfl(wl, q2), e3 = di * __shfl(wl, q3);
            unsigned u0 = h[(size_t)s0 * 32 + fp];
            unsigned u1 = h[(size_t)s1 * 32 + fp];
            unsigned u2 = h[(size_t)s2 * 32 + fp];
            unsigned u3 = h[(size_t)s3 * 32 + fp];
            float2 v0 = bfpair(u0), v1 = bfpair(u1), v2 = bfpair(u2), v3 = bfpair(u3);
            ax = fmaf(e0, v0.x, ax); ay = fmaf(e0, v0.y, ay);
            ax = fmaf(e1, v1.x, ax); ay = fmaf(e1, v1.y, ay);
            ax = fmaf(e2, v2.x, ax); ay = fmaf(e2, v2.y, ay);
            ax = fmaf(e3, v3.x, ax); ay = fmaf(e3, v3.y, ay);
        }
        for (; j < m; j += 2) {
            int q = j + half;
            int s = __shfl(sl, q & 63);
            float we = di * __shfl(wl, q & 63);
            float2 v = bfpair(h[(size_t)s * 32 + fp]);
            ax = fmaf(we, v.x, ax); ay = fmaf(we, v.y, ay);
        }
    }
    ax += __shfl_xor(ax, 32, 64);
    ay += __shfl_xor(ay, 32, 64);
    if (half == 0) {
        float2 r = make_float2(ax + bias[fp * 2], ay + bias[fp * 2 + 1]);
        *(float2*)&out[(size_t)node * 64 + fp * 2] = r;
    }
}

// ---------- launch ----------
extern "C" void kernel_launch(void* const* d_in, const int* in_sizes, int n_in,
                              void* d_out, int out_size, void* d_ws, size_t ws_size,
                              hipStream_t stream) {
    const float* x  = (const float*)d_in[0];
    const void*  ei = d_in[1];
    const float* W1 = (const float*)d_in[2];
    const float* b1 = (const float*)d_in[3];
    const float* W2 = (const float*)d_in[4];
    const float* b2 = (const float*)d_in[5];

    const int N = N_NODES;
    const int E = in_sizes[1] / 2;

    char* w = (char*)d_ws;
    size_t off = 0;
    auto take = [&](size_t bytes) {
        void* p = w + off;
        off = (off + bytes + 255) & ~(size_t)255;
        return p;
    };
    int*   flag    = (int*)take(sizeof(int));
    int*   cnt     = (int*)take((size_t)N * 4);
    int*   row_ptr = (int*)take((size_t)N * 4);
    int*   pos     = (int*)take((size_t)N * 4);
    int*   bsum    = (int*)take(128 * 4);
    float* dinv    = (float*)take((size_t)N * 4);
    int*   esrc    = (int*)take((size_t)E * 4);
    int*   edst    = (int*)take((size_t)E * 4);
    int*   colv    = (int*)take((size_t)E * 4);
    unsigned short* w1bf = (unsigned short*)take(128 * 128 * 2);
    unsigned short* w2bf = (unsigned short*)take(64 * 128 * 2);
    unsigned* hr   = (unsigned*)take((size_t)N * 64 * 4);   // bf16 [N][128]
    unsigned* h2   = (unsigned*)take((size_t)N * 32 * 4);   // bf16 [N][64]
    (void)ws_size; (void)n_in; (void)out_size;

    unsigned* h1 = (unsigned*)d_out;  // bf16 [N][128] in d_out, dead before agg2 writes

    const int nscan = (N + 1023) / 1024;  // 98

    detect64_k<<<1, 64, 0, stream>>>((const unsigned long long*)ei, flag);
    zero_k<<<(N + 255) / 256, 256, 0, stream>>>(cnt, N);
    convcount_k<<<(E + 255) / 256, 256, 0, stream>>>(ei, flag, esrc, edst, cnt, E);
    scan1_k<<<nscan, 256, 0, stream>>>(cnt, row_ptr, bsum, N);
    scan2_k<<<1, 256, 0, stream>>>(bsum, nscan);
    scan3_k<<<nscan, 256, 0, stream>>>(bsum, cnt, row_ptr, pos, dinv, N);
    fill_xcd_k<<<1024, 256, 0, stream>>>(esrc, edst, pos, colv, E);
    prep_w_k<<<64, 256, 0, stream>>>(W1, W2, w1bf, w2bf);

    gemm1_k<<<(N + 63) / 64, 256, 0, stream>>>(x, w1bf, h1, N);
    agg1_k<<<(N + 3) / 4, 256, 0, stream>>>(h1, row_ptr, cnt, colv, dinv, b1, hr, N, E);
    gemm2_k<<<(N + 63) / 64, 256, 0, stream>>>(hr, w2bf, h2, N);
    agg2_k<<<(N + 3) / 4, 256, 0, stream>>>(h2, row_ptr, cnt, colv, dinv, b2, (float*)d_out, N, E);
}